// Round 10
// baseline (1528.210 us; speedup 1.0000x reference)
//
#include <hip/hip_runtime.h>
#include <math.h>

#define DEV static __device__ __forceinline__

constexpr int NN = 8192;    // nodes
constexpr int NE = 32768;   // edges
constexpr int NB = 32;      // graphs

using short8 = __attribute__((ext_vector_type(8))) short;
using f32x4  = __attribute__((ext_vector_type(4))) float;

DEV ushort f2bf(float f) {  // round-to-nearest-even f32 -> bf16 bits
  unsigned u = __float_as_uint(f);
  unsigned r = (u + 0x7FFFu + ((u >> 16) & 1u)) >> 16;
  return (ushort)r;
}
DEV float bf2f(ushort h) { return __uint_as_float(((unsigned)h) << 16); }

// split p[8] into bf16 hi + bf16 residual
DEV void split8(const float* p, short8& hi, short8& lo) {
#pragma unroll
  for (int j = 0; j < 8; ++j) {
    const ushort h = f2bf(p[j]);
    hi[j] = (short)h;
    const float r = p[j] - bf2f(h);
    lo[j] = (short)(__float_as_uint(r) >> 16);
  }
}

DEV int lidx_of(int c) { return (c == 0) ? 0 : (c < 4) ? 1 : (c < 9) ? 2 : 3; }

DEV void real_sh_f(float x, float y, float z, float* Y) {
  const float s3  = 1.7320508075688772f;
  const float s5  = 2.23606797749979f;
  const float s15 = 3.872983346207417f;
  Y[0] = 1.f;
  Y[1] = s3 * y;  Y[2] = s3 * z;  Y[3] = s3 * x;
  Y[4] = s15 * x * y;
  Y[5] = s15 * y * z;
  Y[6] = 0.5f * s5 * (3.f * z * z - 1.f);
  Y[7] = s15 * x * z;
  Y[8] = 0.5f * s15 * (x * x - y * y);
  Y[9]  = 2.091650066335189f * y * (3.f * x * x - y * y);
  Y[10] = 10.246950765959598f * x * y * z;
  Y[11] = 1.6201851746019651f * y * (5.f * z * z - 1.f);
  Y[12] = 1.3228756555322954f * (5.f * z * z * z - 3.f * z);
  Y[13] = 1.6201851746019651f * x * (5.f * z * z - 1.f);
  Y[14] = 5.123475382979799f * (x * x - y * y) * z;
  Y[15] = 2.091650066335189f * x * (x * x - 3.f * y * y);
}

// ---------------- edge geometry: Y, u, cut + degree histogram ----------------
__global__ __launch_bounds__(256) void k_edge_prep(
    const float* __restrict__ pos, const int* __restrict__ esrc,
    const int* __restrict__ edst, float* __restrict__ u_, float* __restrict__ cut_,
    float* __restrict__ Y_, int* __restrict__ cnt) {
  const int e = blockIdx.x * 256 + threadIdx.x;
  if (e >= NE) return;
  const int s = esrc[e], t = edst[e];
  const float ex = pos[t * 3 + 0] - pos[s * 3 + 0];
  const float ey = pos[t * 3 + 1] - pos[s * 3 + 1];
  const float ez = pos[t * 3 + 2] - pos[s * 3 + 2];
  const float d = sqrtf(ex * ex + ey * ey + ez * ez) + 1e-9f;
  const float inv = 1.f / d;
  float Y[16];
  real_sh_f(ex * inv, ey * inv, ez * inv, Y);
#pragma unroll
  for (int c = 0; c < 16; ++c) Y_[(size_t)e * 16 + c] = Y[c];
  const float u = d / 3.5f;
  u_[e] = u;
  cut_[e] = (u < 1.f) ? 0.5f * (cosf(3.14159265358979323846f * u) + 1.f) : 0.f;
  atomicAdd(&cnt[t], 1);
}

// ---------------- CSR build: scan + fill ----------------
__global__ __launch_bounds__(256) void k_scan(const int* __restrict__ cnt,
                                              int* __restrict__ offs,
                                              int* __restrict__ cursor) {
  __shared__ int part[256];
  const int t = threadIdx.x;
  int s = 0;
  for (int i = 0; i < 32; ++i) s += cnt[t * 32 + i];
  part[t] = s;
  __syncthreads();
  if (t == 0) {
    int run = 0;
    for (int i = 0; i < 256; ++i) { int v = part[i]; part[i] = run; run += v; }
    offs[NN] = run;
  }
  __syncthreads();
  int run = part[t];
  for (int i = 0; i < 32; ++i) {
    const int idx = t * 32 + i;
    offs[idx] = run;
    cursor[idx] = run;
    run += cnt[idx];
  }
}

__global__ __launch_bounds__(256) void k_fill(const int* __restrict__ edst,
                                              int* __restrict__ cursor,
                                              int* __restrict__ elist) {
  const int e = blockIdx.x * 256 + threadIdx.x;
  if (e < NE) {
    const int p = atomicAdd(&cursor[edst[e]], 1);
    elist[p] = e;
  }
}

// ---------------- W2^T bf16 hi/lo prep ----------------
template <bool IS2>
__global__ __launch_bounds__(256) void k_prep_w2t(const float* __restrict__ W2,
                                                  ushort* __restrict__ Th,
                                                  ushort* __restrict__ Tl) {
  const int idx = blockIdx.x * 256 + threadIdx.x;
  if (idx >= 128 * 1024) return;
  const int o = idx >> 10, kf = idx & 1023;
  const float v = IS2 ? W2[(size_t)(kf >> 4) * 2176 + (kf & 15) * 128 + o]
                      : W2[(size_t)kf * 128 + o];
  const ushort h = f2bf(v);
  Th[idx] = h;
  Tl[idx] = (ushort)(__float_as_uint(v - bf2f(h)) >> 16);
}

__global__ __launch_bounds__(256) void k_prep_selfw(const float* __restrict__ W2,
                                                    ushort* __restrict__ Sh,
                                                    ushort* __restrict__ Sl) {
  const int idx = blockIdx.x * 256 + threadIdx.x;
  if (idx >= 128 * 64) return;
  const int o = idx >> 6, k = idx & 63;
  const float v = W2[(size_t)k * 2176 + 2048 + o];
  const ushort h = f2bf(v);
  Sh[idx] = h;
  Sl[idx] = (ushort)(__float_as_uint(v - bf2f(h)) >> 16);
}

// ---------------- per-edge bilinear GEMM via split-bf16 MFMA ----------------
// Block: 32 edges (2 m-tiles), 4 waves; wave w owns n-tiles {2w, 2w+1} (N=32).
// Register-double-buffered: B-frags (global) and hs (LDS) prefetched 1 iter ahead.
template <bool IS2>
__global__ __launch_bounds__(256) void k_msg_mfma(
    const float* __restrict__ u_, const float* __restrict__ cut_,
    const float* __restrict__ W1, const float* __restrict__ bvec,
    const ushort* __restrict__ W2Th, const ushort* __restrict__ W2Tl,
    const ushort* __restrict__ SWh, const ushort* __restrict__ SWl,
    const float* __restrict__ feat16, const int* __restrict__ esrc,
    float* __restrict__ t_, float* __restrict__ self_) {
  __shared__ float hhL[32 * 65];
  __shared__ float nfL[32 * 17];
  __shared__ float uL[32], cL[32];
  __shared__ int sL[32];
  const int tid = threadIdx.x;
  const int e0 = blockIdx.x * 32;
  if (tid < 32) {
    uL[tid] = u_[e0 + tid];
    cL[tid] = cut_[e0 + tid];
    sL[tid] = esrc[e0 + tid];
  }
  __syncthreads();
  for (int i = tid; i < 32 * 64; i += 256) {
    const int e = i >> 6, k = i & 63;
    hhL[e * 65 + k] = fmaxf(fmaf(uL[e], W1[k], bvec[k]), 0.f) * cL[e];
  }
  for (int i = tid; i < 32 * 16; i += 256) {
    const int e = i >> 4, f = i & 15;
    nfL[e * 17 + f] = feat16[(size_t)sL[e] * 16 + f];
  }
  __syncthreads();

  const int lane = tid & 63, wv = tid >> 6;
  const int lr = lane & 15, lg = lane >> 4;
  const int n0 = wv * 2;

  if (IS2) {
    f32x4 sacc[2][2];
#pragma unroll
    for (int mt = 0; mt < 2; ++mt)
#pragma unroll
      for (int n = 0; n < 2; ++n) {
        f32x4 zz = {0.f, 0.f, 0.f, 0.f};
        sacc[mt][n] = zz;
      }
#pragma unroll
    for (int ks2 = 0; ks2 < 2; ++ks2) {
      short8 ash[2], asl[2];
#pragma unroll
      for (int mt = 0; mt < 2; ++mt) {
        float p[8];
        const float* hp = &hhL[(mt * 16 + lr) * 65 + ks2 * 32 + lg * 8];
#pragma unroll
        for (int j = 0; j < 8; ++j) p[j] = hp[j];
        split8(p, ash[mt], asl[mt]);
      }
#pragma unroll
      for (int n = 0; n < 2; ++n) {
        const short8 bh = *(const short8*)&SWh[((n0 + n) * 16 + lr) * 64 + ks2 * 32 + lg * 8];
        const short8 bl = *(const short8*)&SWl[((n0 + n) * 16 + lr) * 64 + ks2 * 32 + lg * 8];
#pragma unroll
        for (int mt = 0; mt < 2; ++mt) {
          sacc[mt][n] = __builtin_amdgcn_mfma_f32_16x16x32_bf16(ash[mt], bh, sacc[mt][n], 0, 0, 0);
          sacc[mt][n] = __builtin_amdgcn_mfma_f32_16x16x32_bf16(asl[mt], bh, sacc[mt][n], 0, 0, 0);
          sacc[mt][n] = __builtin_amdgcn_mfma_f32_16x16x32_bf16(ash[mt], bl, sacc[mt][n], 0, 0, 0);
        }
      }
    }
#pragma unroll
    for (int mt = 0; mt < 2; ++mt)
#pragma unroll
      for (int n = 0; n < 2; ++n)
#pragma unroll
        for (int i = 0; i < 4; ++i)
          self_[(size_t)(e0 + mt * 16 + lg * 4 + i) * 128 + (n0 + n) * 16 + lr] =
              sacc[mt][n][i] * 0.5f;
  }

  float nf8[2][8];
#pragma unroll
  for (int mt = 0; mt < 2; ++mt)
#pragma unroll
    for (int j = 0; j < 8; ++j)
      nf8[mt][j] = nfL[(mt * 16 + lr) * 17 + (lg & 1) * 8 + j];

  f32x4 acc[2][2];
#pragma unroll
  for (int mt = 0; mt < 2; ++mt)
#pragma unroll
    for (int n = 0; n < 2; ++n) {
      f32x4 zz = {0.f, 0.f, 0.f, 0.f};
      acc[mt][n] = zz;
    }

  // B-row base addresses for this wave's two n-tiles
  const ushort* bh_base[2] = {
    &W2Th[(size_t)((n0 + 0) * 16 + lr) * 1024 + lg * 8],
    &W2Th[(size_t)((n0 + 1) * 16 + lr) * 1024 + lg * 8]};
  const ushort* bl_base[2] = {
    &W2Tl[(size_t)((n0 + 0) * 16 + lr) * 1024 + lg * 8],
    &W2Tl[(size_t)((n0 + 1) * 16 + lr) * 1024 + lg * 8]};
  const float* hs_base[2] = {&hhL[(0 * 16 + lr) * 65 + (lg >> 1)],
                             &hhL[(1 * 16 + lr) * 65 + (lg >> 1)]};

  // software pipeline: prefetch B and hs for next iter while computing current
  short8 bhr[2][2], blr[2][2];  // [buf][n]
  float hsr[2][2];              // [buf][mt]
#pragma unroll
  for (int n = 0; n < 2; ++n) {
    bhr[0][n] = *(const short8*)(bh_base[n]);
    blr[0][n] = *(const short8*)(bl_base[n]);
  }
#pragma unroll
  for (int mt = 0; mt < 2; ++mt) hsr[0][mt] = hs_base[mt][0];

  for (int ks = 0; ks < 32; ++ks) {
    const int cur = ks & 1, nxt = cur ^ 1;
    if (ks < 31) {
      const int koff = (ks + 1) * 32;
#pragma unroll
      for (int n = 0; n < 2; ++n) {
        bhr[nxt][n] = *(const short8*)(bh_base[n] + koff);
        blr[nxt][n] = *(const short8*)(bl_base[n] + koff);
      }
#pragma unroll
      for (int mt = 0; mt < 2; ++mt) hsr[nxt][mt] = hs_base[mt][2 * (ks + 1)];
    }
    short8 ah[2], al[2];
#pragma unroll
    for (int mt = 0; mt < 2; ++mt) {
      const float hs = hsr[cur][mt];
      float p[8];
#pragma unroll
      for (int j = 0; j < 8; ++j) p[j] = hs * nf8[mt][j];
      split8(p, ah[mt], al[mt]);
    }
#pragma unroll
    for (int n = 0; n < 2; ++n) {
      const short8 bh = bhr[cur][n];
      const short8 bl = blr[cur][n];
#pragma unroll
      for (int mt = 0; mt < 2; ++mt) {
        acc[mt][n] = __builtin_amdgcn_mfma_f32_16x16x32_bf16(ah[mt], bh, acc[mt][n], 0, 0, 0);
        acc[mt][n] = __builtin_amdgcn_mfma_f32_16x16x32_bf16(al[mt], bh, acc[mt][n], 0, 0, 0);
        acc[mt][n] = __builtin_amdgcn_mfma_f32_16x16x32_bf16(ah[mt], bl, acc[mt][n], 0, 0, 0);
      }
    }
  }
#pragma unroll
  for (int mt = 0; mt < 2; ++mt)
#pragma unroll
    for (int n = 0; n < 2; ++n)
#pragma unroll
      for (int i = 0; i < 4; ++i)
        t_[(size_t)(e0 + mt * 16 + lg * 4 + i) * 128 + (n0 + n) * 16 + lr] =
            acc[mt][n][i] * 0.125f;  // 1/sqrt(F)/deg
}

// ---------------- gather (segment sum over incoming edges) + gate ----------------
__global__ __launch_bounds__(256) void k_gather1(
    const float* __restrict__ t_, const float* __restrict__ Y_,
    const int* __restrict__ offs, const int* __restrict__ elist,
    float* __restrict__ h1, float* __restrict__ h1s) {
  __shared__ float tL[128], YL[16], sG[32];
  const int n = blockIdx.x, tid = threadIdx.x;
  const int beg = offs[n], end = offs[n + 1];
  const int cc = tid & 15;
  const int lx = lidx_of(cc);
  const int o0 = ((tid >> 4) << 2) + lx;
  const int o1 = o0 + 64;
  float a0 = 0.f, a1 = 0.f;
  for (int ei = beg; ei < end; ++ei) {
    const int e = elist[ei];
    __syncthreads();
    if (tid < 128) tL[tid] = t_[(size_t)e * 128 + tid];
    else if (tid < 144) YL[tid - 128] = Y_[(size_t)e * 16 + tid - 128];
    __syncthreads();
    const float yv = YL[cc];
    a0 = fmaf(tL[o0], yv, a0);
    a1 = fmaf(tL[o1], yv, a1);
  }
  if (cc == 0) { sG[tid >> 4] = a0; sG[(tid >> 4) + 16] = a1; }
  __syncthreads();
  const float s0 = sG[tid >> 4], s1 = sG[(tid >> 4) + 16];
  const float r0 = (cc == 0) ? fmaxf(a0, 0.f) : a0 * (1.f / (1.f + expf(-s0)));
  const float r1 = (cc == 0) ? fmaxf(a1, 0.f) : a1 * (1.f / (1.f + expf(-s1)));
  h1[(size_t)n * 512 + tid] = r0;
  h1[(size_t)n * 512 + tid + 256] = r1;
  if ((tid & 31) == 0) {
    h1s[n * 16 + (tid >> 5)] = r0;
    h1s[n * 16 + (tid >> 5) + 8] = r1;
  }
}

__global__ __launch_bounds__(256) void k_gather2(
    const float* __restrict__ t_, const float* __restrict__ self_,
    const float* __restrict__ Y_, const float* __restrict__ h1,
    const int* __restrict__ offs, const int* __restrict__ elist,
    const int* __restrict__ esrc, float* __restrict__ h2) {
  __shared__ float tL[128], wL[128], YL[16], sG[32];
  const int n = blockIdx.x, tid = threadIdx.x;
  const int beg = offs[n], end = offs[n + 1];
  const int cc = tid & 15;
  const int lx = lidx_of(cc);
  const int o0 = ((tid >> 4) << 2) + lx;
  const int o1 = o0 + 64;
  float a0 = 0.f, a1 = 0.f;
  for (int ei = beg; ei < end; ++ei) {
    const int e = elist[ei];
    __syncthreads();
    if (tid < 128) tL[tid] = t_[(size_t)e * 128 + tid];
    else wL[tid - 128] = self_[(size_t)e * 128 + tid - 128];
    if (tid < 16) YL[tid] = Y_[(size_t)e * 16 + tid];
    __syncthreads();
    const int src = esrc[e];
    const float* hr = &h1[(size_t)src * 512];
    const float yv = YL[cc];
    a0 += tL[o0] * yv + hr[tid] * wL[o0];
    a1 += tL[o1] * yv + hr[tid + 256] * wL[o1];
  }
  if (cc == 0) { sG[tid >> 4] = a0; sG[(tid >> 4) + 16] = a1; }
  __syncthreads();
  const float s0 = sG[tid >> 4], s1 = sG[(tid >> 4) + 16];
  const float r0 = (cc == 0) ? fmaxf(a0, 0.f) : a0 * (1.f / (1.f + expf(-s0)));
  const float r1 = (cc == 0) ? fmaxf(a1, 0.f) : a1 * (1.f / (1.f + expf(-s1)));
  h2[(size_t)n * 512 + tid] = r0;
  h2[(size_t)n * 512 + tid + 256] = r1;
}

// ---------------- mean pool over each graph's 256 nodes ----------------
__global__ __launch_bounds__(256) void k_pool(const float* __restrict__ h2,
                                              float* __restrict__ enc) {
  const int b = blockIdx.x, tid = threadIdx.x;
  float a0 = 0.f, a1 = 0.f;
  for (int i = 0; i < 256; ++i) {
    const float* row = &h2[(size_t)(b * 256 + i) * 512];
    a0 += row[tid];
    a1 += row[tid + 256];
  }
  enc[b * 512 + tid] = a0 * (1.f / 256.f);
  enc[b * 512 + tid + 256] = a1 * (1.f / 256.f);
}

// ---------------- z = per-l linear mix of enc (B,32,16) -> (B,16,84) ----------------
__global__ __launch_bounds__(256) void k_zproj(const float* __restrict__ enc,
                                               const float* __restrict__ Wlin,
                                               float* __restrict__ z) {
  __shared__ float eL[512];
  const int b = blockIdx.x, tid = threadIdx.x;
  eL[tid] = enc[b * 512 + tid];
  eL[tid + 256] = enc[b * 512 + tid + 256];
  __syncthreads();
  for (int idx = tid; idx < 16 * 84; idx += 256) {
    const int g = idx / 84, d3 = idx % 84;
    int o0, m0, mo;
    if (d3 < 1)       { o0 = 0;  m0 = 1; mo = 0; }
    else if (d3 < 10) { o0 = 1;  m0 = 3; mo = 1; }
    else if (d3 < 35) { o0 = 10; m0 = 5; mo = 4; }
    else              { o0 = 35; m0 = 7; mo = 9; }
    const int rem = d3 - o0;
    const int jj = rem / m0;
    const int cc2 = rem - jj * m0;
    float a = 0.f;
    for (int mu = 0; mu < 32; ++mu)
      a = fmaf(eL[mu * 16 + mo + cc2], Wlin[(mu * 16 + g) * 16 + mo + jj], a);
    z[(size_t)(b * 16 + g) * 84 + d3] = a * 0.17677669529663687f;  // 1/sqrt(32)
  }
}

// ---------------- SO3 conv as split-bf16 MFMA GEMMs ----------------
template <int FI>
__global__ __launch_bounds__(256) void k_prep_xg(const float* __restrict__ x,
                                                 ushort* __restrict__ Xh,
                                                 ushort* __restrict__ Xl) {
  constexpr int KP0 = (FI + 31) & ~31, KP1 = (3 * FI + 31) & ~31;
  constexpr int KP2 = (5 * FI + 31) & ~31, KP3 = (7 * FI + 31) & ~31;
  constexpr int XO1 = 32 * KP0, XO2 = XO1 + 96 * KP1, XO3 = XO2 + 160 * KP2;
  constexpr int TOT = XO3 + 224 * KP3;
  const int idx = blockIdx.x * 256 + threadIdx.x;
  if (idx >= TOT) return;
  int m, o0, base, KP;
  if (idx < XO1)      { m = 1; o0 = 0;  base = 0;   KP = KP0; }
  else if (idx < XO2) { m = 3; o0 = 1;  base = XO1; KP = KP1; }
  else if (idx < XO3) { m = 5; o0 = 10; base = XO2; KP = KP2; }
  else                { m = 7; o0 = 35; base = XO3; KP = KP3; }
  const int rel = idx - base;
  const int r = rel / KP, k = rel % KP;
  ushort h = 0, lo = 0;
  if (k < FI * m) {
    const int f = k / m, i = k % m, b = r / m, c = r % m;
    const float v = x[((size_t)b * FI + f) * 84 + o0 + i * m + c];
    h = f2bf(v);
    lo = (ushort)(__float_as_uint(v - bf2f(h)) >> 16);
  }
  Xh[idx] = h;
  Xl[idx] = lo;
}

template <int FI, int FO>
__global__ __launch_bounds__(256) void k_prep_psig(const float* __restrict__ psi,
                                                   ushort* __restrict__ Ph,
                                                   ushort* __restrict__ Pl) {
  constexpr int KP0 = (FI + 31) & ~31, KP1 = (3 * FI + 31) & ~31;
  constexpr int KP2 = (5 * FI + 31) & ~31, KP3 = (7 * FI + 31) & ~31;
  constexpr int PO1 = FO * KP0, PO2 = PO1 + 3 * FO * KP1, PO3 = PO2 + 5 * FO * KP2;
  constexpr int TOT = PO3 + 7 * FO * KP3;
  const int idx = blockIdx.x * 256 + threadIdx.x;
  if (idx >= TOT) return;
  int m, o0, base, KP;
  if (idx < PO1)      { m = 1; o0 = 0;  base = 0;   KP = KP0; }
  else if (idx < PO2) { m = 3; o0 = 1;  base = PO1; KP = KP1; }
  else if (idx < PO3) { m = 5; o0 = 10; base = PO2; KP = KP2; }
  else                { m = 7; o0 = 35; base = PO3; KP = KP3; }
  const int rel = idx - base;
  const int n = rel / KP, k = rel % KP;
  ushort h = 0, lo = 0;
  if (k < FI * m) {
    const int f = k / m, i = k % m, g = n / m, j = n % m;
    const float v = psi[((size_t)f * FO + g) * 84 + o0 + i * m + j];
    h = f2bf(v);
    lo = (ushort)(__float_as_uint(v - bf2f(h)) >> 16);
  }
  Ph[idx] = h;
  Pl[idx] = lo;
}

template <int FI, int FO>
__global__ __launch_bounds__(256) void k_conv_gemm(
    const ushort* __restrict__ Xh, const ushort* __restrict__ Xl,
    const ushort* __restrict__ Ph, const ushort* __restrict__ Pl,
    float* __restrict__ out) {
  constexpr int KP0 = (FI + 31) & ~31, KP1 = (3 * FI + 31) & ~31;
  constexpr int KP2 = (5 * FI + 31) & ~31, KP3 = (7 * FI + 31) & ~31;
  constexpr int XO1 = 32 * KP0, XO2 = XO1 + 96 * KP1, XO3 = XO2 + 160 * KP2;
  constexpr int PO1 = FO * KP0, PO2 = PO1 + 3 * FO * KP1, PO3 = PO2 + 5 * FO * KP2;
  constexpr int NT0 = 1 * (FO / 32), NT1 = 3 * (3 * FO / 32);
  constexpr int NT2 = 5 * (5 * FO / 32), NT3 = 7 * (7 * FO / 32);
  constexpr int TB1 = NT0, TB2 = TB1 + NT1, TB3 = TB2 + NT2, TOT = TB3 + NT3;

  const int wt = blockIdx.x * 4 + (threadIdx.x >> 6);
  if (wt >= TOT) return;
  int m, o0, Mt, KP, Xo, Po, loc;
  if (wt < TB1)      { m = 1; o0 = 0;  Mt = 1; KP = KP0; Xo = 0;   Po = 0;   loc = wt; }
  else if (wt < TB2) { m = 3; o0 = 1;  Mt = 3; KP = KP1; Xo = XO1; Po = PO1; loc = wt - TB1; }
  else if (wt < TB3) { m = 5; o0 = 10; Mt = 5; KP = KP2; Xo = XO2; Po = PO2; loc = wt - TB2; }
  else               { m = 7; o0 = 35; Mt = 7; KP = KP3; Xo = XO3; Po = PO3; loc = wt - TB3; }
  const int mt0 = (loc % Mt) * 32;
  const int nt0 = (loc / Mt) * 32;
  const int lane = threadIdx.x & 63, lr = lane & 15, lg = lane >> 4;

  f32x4 acc[2][2];
#pragma unroll
  for (int mt = 0; mt < 2; ++mt)
#pragma unroll
    for (int nt = 0; nt < 2; ++nt) {
      f32x4 zz = {0.f, 0.f, 0.f, 0.f};
      acc[mt][nt] = zz;
    }

  const int nks = KP >> 5;
  for (int ks = 0; ks < nks; ++ks) {
    short8 ah[2], al[2], bh[2], bl[2];
#pragma unroll
    for (int t = 0; t < 2; ++t) {
      const size_t xa = (size_t)Xo + (size_t)(mt0 + t * 16 + lr) * KP + ks * 32 + lg * 8;
      ah[t] = *(const short8*)&Xh[xa];
      al[t] = *(const short8*)&Xl[xa];
      const size_t pa = (size_t)Po + (size_t)(nt0 + t * 16 + lr) * KP + ks * 32 + lg * 8;
      bh[t] = *(const short8*)&Ph[pa];
      bl[t] = *(const short8*)&Pl[pa];
    }
#pragma unroll
    for (int nt = 0; nt < 2; ++nt)
#pragma unroll
      for (int mt = 0; mt < 2; ++mt) {
        acc[mt][nt] = __builtin_amdgcn_mfma_f32_16x16x32_bf16(ah[mt], bh[nt], acc[mt][nt], 0, 0, 0);
        acc[mt][nt] = __builtin_amdgcn_mfma_f32_16x16x32_bf16(al[mt], bh[nt], acc[mt][nt], 0, 0, 0);
        acc[mt][nt] = __builtin_amdgcn_mfma_f32_16x16x32_bf16(ah[mt], bl[nt], acc[mt][nt], 0, 0, 0);
      }
  }

  const float scale = 1.f / sqrtf((float)(FI * m));
#pragma unroll
  for (int mt = 0; mt < 2; ++mt)
#pragma unroll
    for (int nt = 0; nt < 2; ++nt)
#pragma unroll
      for (int i = 0; i < 4; ++i) {
        const int R = mt0 + mt * 16 + lg * 4 + i;
        const int C2 = nt0 + nt * 16 + lr;
        const int b = R / m, c = R - b * m;
        const int g = C2 / m, j = C2 - g * m;
        out[((size_t)b * FO + g) * 84 + o0 + j * m + c] = acc[mt][nt][i] * scale;
      }
}

// ---------------- weight prep for MFMA act ----------------
__global__ __launch_bounds__(256) void k_prep_gt(const float* __restrict__ Gt,
                                                 ushort* __restrict__ GtT) {
  const int idx = blockIdx.x * 256 + threadIdx.x;
  if (idx >= 4096 * 96) return;
  const int g = idx / 96, k = idx % 96;
  GtT[idx] = (k < 84) ? f2bf(Gt[(size_t)k * 4096 + g]) : (ushort)0;
}
__global__ __launch_bounds__(256) void k_prep_gf(const float* __restrict__ Gf,
                                                 ushort* __restrict__ GfT) {
  const int idx = blockIdx.x * 256 + threadIdx.x;
  if (idx >= 96 * 4096) return;
  const int d = idx / 4096, g = idx % 4096;
  GfT[idx] = (d < 84) ? f2bf(Gf[(size_t)g * 84 + d]) : (ushort)0;
}
__global__ __launch_bounds__(256) void k_cvtx(const float* __restrict__ x,
                                              ushort* __restrict__ Xb, int total) {
  const int idx = blockIdx.x * 256 + threadIdx.x;
  if (idx >= total) return;
  const int r = idx / 96, k = idx % 96;
  Xb[idx] = (k < 84) ? f2bf(x[(size_t)r * 84 + k]) : (ushort)0;
}

// ---------------- SO3 act via bf16 MFMA (fused, g-split partials) ----------------
template <int GS>
__global__ __launch_bounds__(256) void k_act_mfma(
    const ushort* __restrict__ Xb, const ushort* __restrict__ GtT,
    const ushort* __restrict__ GfT, float* __restrict__ part, int NR) {
  constexpr int CPB = 64 / GS;
  __shared__ __align__(16) ushort ldsGt[64 * 104];
  __shared__ __align__(16) ushort ldsH[128 * 72];
  __shared__ __align__(16) ushort ldsGf[96 * 72];
  const int tid = threadIdx.x;
  const int gs = blockIdx.x;
  const int row0 = blockIdx.y * 128;
  const int lane = tid & 63, wv = tid >> 6;
  const int lr = lane & 15, lg = lane >> 4;
  const int m0 = wv * 32;

  short8 a1[2][3];
#pragma unroll
  for (int mt = 0; mt < 2; ++mt)
#pragma unroll
    for (int ks = 0; ks < 3; ++ks)
      a1[mt][ks] = *(const short8*)&Xb[(size_t)(row0 + m0 + mt * 16 + lr) * 96 +
                                       ks * 32 + lg * 8];

  f32x4 acc2[6][2];
#pragma unroll
  for (int m2 = 0; m2 < 6; ++m2)
#pragma unroll
    for (int n2 = 0; n2 < 2; ++n2) {
      f32x4 zz = {0.f, 0.f, 0.f, 0.f};
      acc2[m2][n2] = zz;
    }

  for (int ch = gs * CPB; ch < (gs + 1) * CPB; ++ch) {
    const int g0 = ch * 64;
    __syncthreads();
    for (int i = tid; i < 768; i += 256) {
      const int row = i / 12, c = i % 12;
      *(uint4*)&ldsGt[row * 104 + c * 8] =
          *(const uint4*)&GtT[(size_t)(g0 + row) * 96 + c * 8];
    }
    for (int i = tid; i < 768; i += 256) {
      const int row = i / 8, c = i % 8;
      *(uint4*)&ldsGf[row * 72 + c * 8] =
          *(const uint4*)&GfT[(size_t)row * 4096 + g0 + c * 8];
    }
    __syncthreads();
#pragma unroll
    for (int n = 0; n < 4; ++n) {
      short8 b[3];
#pragma unroll
      for (int ks = 0; ks < 3; ++ks)
        b[ks] = *(const short8*)&ldsGt[(n * 16 + lr) * 104 + ks * 32 + lg * 8];
#pragma unroll
      for (int mt = 0; mt < 2; ++mt) {
        f32x4 c1 = {0.f, 0.f, 0.f, 0.f};
#pragma unroll
        for (int ks = 0; ks < 3; ++ks)
          c1 = __builtin_amdgcn_mfma_f32_16x16x32_bf16(a1[mt][ks], b[ks], c1, 0, 0, 0);
        ushort* hp = &ldsH[(m0 + mt * 16 + lg * 4) * 72 + n * 16 + lr];
#pragma unroll
        for (int i = 0; i < 4; ++i) hp[i * 72] = f2bf(fmaxf(c1[i], 0.f));
      }
    }
#pragma unroll
    for (int k2 = 0; k2 < 2; ++k2) {
      short8 bh[2];
#pragma unroll
      for (int n2 = 0; n2 < 2; ++n2)
        bh[n2] = *(const short8*)&ldsH[(m0 + n2 * 16 + lr) * 72 + k2 * 32 + lg * 8];
#pragma unroll
      for (int m2 = 0; m2 < 6; ++m2) {
        const short8 a2 = *(const short8*)&ldsGf[(m2 * 16 + lr) * 72 + k2 * 32 + lg * 8];
        acc2[m2][0] = __builtin_amdgcn_mfma_f32_16x16x32_bf16(a2, bh[0], acc2[m2][0], 0, 0, 0);
        acc2[m2][1] = __builtin_amdgcn_mfma_f32_16x16x32_bf16(a2, bh[1], acc2[m2][1], 0, 0, 0);
      }
    }
  }
#pragma unroll
  for (int m2 = 0; m2 < 6; ++m2)
#pragma unroll
    for (int n2 = 0; n2 < 2; ++n2)
#pragma unroll
      for (int i = 0; i < 4; ++i) {
        const int d = m2 * 16 + lg * 4 + i;
        if (d < 84) {
          const int r = row0 + m0 + n2 * 16 + lr;
          part[((size_t)gs * NR + r) * 84 + d] = acc2[m2][n2][i];
        }
      }
}

template <int GS>
__global__ __launch_bounds__(256) void k_act_reduce(const float* __restrict__ part,
                                                    float* __restrict__ out, int total) {
  const int i = blockIdx.x * 256 + threadIdx.x;
  if (i < total) {
    float s = part[i];
#pragma unroll
    for (int g = 1; g < GS; ++g) s += part[(size_t)g * total + i];
    out[i] = s * (1.f / (9.16515138991168f * 64.f));
  }
}

// ---------------- final: Ws2 contraction + orientation SH dot ----------------
__global__ __launch_bounds__(256) void k_final(const float* __restrict__ x,
                                               const float* __restrict__ Ws2,
                                               const float* __restrict__ orient,
                                               float* __restrict__ outp) {
  __shared__ float red[256][16];
  const int b = blockIdx.x, tid = threadIdx.x;
  const float* xr = &x[(size_t)(b * 256 + tid) * 84];
  const float* wr = &Ws2[tid * 16];
  float acc[16];
#pragma unroll
  for (int c = 0; c < 16; ++c) acc[c] = 0.f;
  acc[0] = fmaf(xr[0], wr[0], acc[0]);
#pragma unroll
  for (int i = 0; i < 3; ++i) {
    const float w = wr[1 + i];
#pragma unroll
    for (int c = 0; c < 3; ++c) acc[1 + c] = fmaf(xr[1 + i * 3 + c], w, acc[1 + c]);
  }
#pragma unroll
  for (int i = 0; i < 5; ++i) {
    const float w = wr[4 + i];
#pragma unroll
    for (int c = 0; c < 5; ++c) acc[4 + c] = fmaf(xr[10 + i * 5 + c], w, acc[4 + c]);
  }
#pragma unroll
  for (int i = 0; i < 7; ++i) {
    const float w = wr[9 + i];
#pragma unroll
    for (int c = 0; c < 7; ++c) acc[9 + c] = fmaf(xr[35 + i * 7 + c], w, acc[9 + c]);
  }
#pragma unroll
  for (int c = 0; c < 16; ++c) red[tid][c] = acc[c];
  __syncthreads();
  for (int off = 128; off > 0; off >>= 1) {
    if (tid < off)
#pragma unroll
      for (int c = 0; c < 16; ++c) red[tid][c] += red[tid + off][c];
    __syncthreads();
  }
  if (tid == 0) {
    const float aa = orient[b * 2 + 0], rr = orient[b * 2 + 1];
    float Y[16];
    real_sh_f(-sinf(aa) * cosf(rr), -sinf(aa) * sinf(rr), -cosf(aa), Y);
    const float sc1 = 1.f / 16.f;
    const float sc3 = 1.f / (16.f * 1.7320508075688772f);
    const float sc5 = 1.f / (16.f * 2.23606797749979f);
    const float sc7 = 1.f / (16.f * 2.6457513110645907f);
    float o = red[0][0] * sc1 * Y[0];
#pragma unroll
    for (int c = 1; c < 4; ++c) o += red[0][c] * sc3 * Y[c];
#pragma unroll
    for (int c = 4; c < 9; ++c) o += red[0][c] * sc5 * Y[c];
#pragma unroll
    for (int c = 9; c < 16; ++c) o += red[0][c] * sc7 * Y[c];
    outp[b] = o;
  }
}

extern "C" void kernel_launch(void* const* d_in, const int* in_sizes, int n_in,
                              void* d_out, int out_size, void* d_ws, size_t ws_size,
                              hipStream_t stream) {
  const float* node_feat = (const float*)d_in[0];
  const float* pos       = (const float*)d_in[1];
  const float* orient    = (const float*)d_in[2];
  const float* rad1_W1   = (const float*)d_in[3];
  const float* rad1_b    = (const float*)d_in[4];
  const float* rad1_W2   = (const float*)d_in[5];
  const float* rad2_W1   = (const float*)d_in[6];
  const float* rad2_b    = (const float*)d_in[7];
  const float* rad2_W2   = (const float*)d_in[8];
  const float* Wlin      = (const float*)d_in[9];
  const float* psi1      = (const float*)d_in[10];
  const float* psi2      = (const float*)d_in[11];
  const float* psi3      = (const float*)d_in[12];
  const float* G_to      = (const float*)d_in[13];
  const float* G_from    = (const float*)d_in[14];
  const float* Ws2       = (const float*)d_in[15];
  const int*   esrc      = (const int*)d_in[16];
  const int*   edst      = (const int*)d_in[17];

  float* w = (float*)d_ws;
  size_t off = 0;
  float* u_    = w + off; off += NE;
  float* cut_  = w + off; off += NE;
  float* Y_    = w + off; off += (size_t)NE * 16;   // later: Xp hi/lo (bf16)
  float* t_    = w + off; off += (size_t)NE * 128;  // t1/t2; later act partials
  float* self_ = w + off; off += (size_t)NE * 128;
  float* h1    = w + off; off += (size_t)NN * 512;  // later: GtT/GfT/Xb (bf16)
  float* h1s   = w + off; off += (size_t)NN * 16;
  float* h2    = w + off; off += (size_t)NN * 512;  // later: Psi-p hi/lo (bf16)
  float* enc   = w + off; off += (size_t)NB * 512;
  float* z     = w + off; off += (size_t)NB * 16 * 84;
  float* xb1   = w + off; off += (size_t)NB * 256 * 84;
  float* xb2   = w + off; off += (size_t)NB * 256 * 84;
  int* cnt    = (int*)(w + off); off += NN;
  int* offs   = (int*)(w + off); off += NN + 1;
  int* cursor = (int*)(w + off); off += NN;
  int* elist  = (int*)(w + off); off += NE;
  ushort* W2Th = (ushort*)(w + off); off += 65536;
  ushort* W2Tl = (ushort*)(w + off); off += 65536;
  ushort* SWh  = (ushort*)(w + off); off += 4096;
  ushort* SWl  = (ushort*)(w + off); off += 4096;

  // reuse of dead buffers during conv/act chain:
  float* part = t_;
  ushort* GtT = (ushort*)h1;
  ushort* GfT = GtT + 4096 * 96;
  ushort* Xb  = GfT + 96 * 4096;
  ushort* Xph = (ushort*)Y_;
  ushort* Xpl = Xph + 344064;
  ushort* Pph = (ushort*)h2;
  ushort* Ppl = Pph + 2752512;

  hipMemsetAsync(cnt, 0, NN * sizeof(int), stream);
  k_edge_prep<<<NE / 256, 256, 0, stream>>>(pos, esrc, edst, u_, cut_, Y_, cnt);
  k_scan<<<1, 256, 0, stream>>>(cnt, offs, cursor);
  k_fill<<<NE / 256, 256, 0, stream>>>(edst, cursor, elist);

  k_prep_w2t<false><<<512, 256, 0, stream>>>(rad1_W2, W2Th, W2Tl);
  k_msg_mfma<false><<<NE / 32, 256, 0, stream>>>(u_, cut_, rad1_W1, rad1_b, W2Th, W2Tl,
                                                 nullptr, nullptr, node_feat, esrc,
                                                 t_, nullptr);
  k_gather1<<<NN, 256, 0, stream>>>(t_, Y_, offs, elist, h1, h1s);

  k_prep_w2t<true><<<512, 256, 0, stream>>>(rad2_W2, W2Th, W2Tl);
  k_prep_selfw<<<32, 256, 0, stream>>>(rad2_W2, SWh, SWl);
  k_msg_mfma<true><<<NE / 32, 256, 0, stream>>>(u_, cut_, rad2_W1, rad2_b, W2Th, W2Tl,
                                                SWh, SWl, h1s, esrc, t_, self_);
  k_gather2<<<NN, 256, 0, stream>>>(t_, self_, Y_, h1, offs, elist, esrc, h2);
  k_pool<<<NB, 256, 0, stream>>>(h2, enc);
  k_zproj<<<NB, 256, 0, stream>>>(enc, Wlin, z);

  k_prep_gt<<<(4096 * 96 + 255) / 256, 256, 0, stream>>>(G_to, GtT);
  k_prep_gf<<<(96 * 4096 + 255) / 256, 256, 0, stream>>>(G_from, GfT);

  // ---- stage 1
  k_prep_psig<16, 64><<<(102400 + 255) / 256, 256, 0, stream>>>(psi1, Pph, Ppl);
  k_prep_xg<16><<<(51200 + 255) / 256, 256, 0, stream>>>(z, Xph, Xpl);
  k_conv_gemm<16, 64><<<42, 256, 0, stream>>>(Xph, Xpl, Pph, Ppl, xb1);
  k_cvtx<<<(2048 * 96 + 255) / 256, 256, 0, stream>>>(xb1, Xb, 2048 * 96);
  k_act_mfma<32><<<dim3(32, 16), 256, 0, stream>>>(Xb, GtT, GfT, part, 2048);
  k_act_reduce<32><<<(2048 * 84 + 255) / 256, 256, 0, stream>>>(part, xb2, 2048 * 84);

  // ---- stage 2
  k_prep_psig<64, 128><<<(688128 + 255) / 256, 256, 0, stream>>>(psi2, Pph, Ppl);
  k_prep_xg<64><<<(172032 + 255) / 256, 256, 0, stream>>>(xb2, Xph, Xpl);
  k_conv_gemm<64, 128><<<84, 256, 0, stream>>>(Xph, Xpl, Pph, Ppl, xb1);
  k_cvtx<<<(4096 * 96 + 255) / 256, 256, 0, stream>>>(xb1, Xb, 4096 * 96);
  k_act_mfma<16><<<dim3(16, 32), 256, 0, stream>>>(Xb, GtT, GfT, part, 4096);
  k_act_reduce<16><<<(4096 * 84 + 255) / 256, 256, 0, stream>>>(part, xb2, 4096 * 84);

  // ---- stage 3
  k_prep_psig<128, 256><<<(2752512 + 255) / 256, 256, 0, stream>>>(psi3, Pph, Ppl);
  k_prep_xg<128><<<(344064 + 255) / 256, 256, 0, stream>>>(xb2, Xph, Xpl);
  k_conv_gemm<128, 256><<<168, 256, 0, stream>>>(Xph, Xpl, Pph, Ppl, xb1);
  k_cvtx<<<(8192 * 96 + 255) / 256, 256, 0, stream>>>(xb1, Xb, 8192 * 96);
  k_act_mfma<8><<<dim3(8, 64), 256, 0, stream>>>(Xb, GtT, GfT, part, 8192);
  k_act_reduce<8><<<(8192 * 84 + 255) / 256, 256, 0, stream>>>(part, xb2, 8192 * 84);

  k_final<<<NB, 256, 0, stream>>>(xb2, Ws2, orient, (float*)d_out);
}

// Round 11
// 429.038 us; speedup vs baseline: 3.5619x; 3.5619x over previous
//
#include <hip/hip_runtime.h>
#include <math.h>

#define DEV static __device__ __forceinline__

constexpr int NN = 8192;    // nodes
constexpr int NE = 32768;   // edges
constexpr int NB = 32;      // graphs

using short8 = __attribute__((ext_vector_type(8))) short;
using f32x4  = __attribute__((ext_vector_type(4))) float;

DEV ushort f2bf(float f) {  // round-to-nearest-even f32 -> bf16 bits
  unsigned u = __float_as_uint(f);
  unsigned r = (u + 0x7FFFu + ((u >> 16) & 1u)) >> 16;
  return (ushort)r;
}
DEV float bf2f(ushort h) { return __uint_as_float(((unsigned)h) << 16); }

// split p[8] into bf16 hi + bf16 residual
DEV void split8(const float* p, short8& hi, short8& lo) {
#pragma unroll
  for (int j = 0; j < 8; ++j) {
    const ushort h = f2bf(p[j]);
    hi[j] = (short)h;
    const float r = p[j] - bf2f(h);
    lo[j] = (short)(__float_as_uint(r) >> 16);
  }
}

DEV int lidx_of(int c) { return (c == 0) ? 0 : (c < 4) ? 1 : (c < 9) ? 2 : 3; }

DEV void real_sh_f(float x, float y, float z, float* Y) {
  const float s3  = 1.7320508075688772f;
  const float s5  = 2.23606797749979f;
  const float s15 = 3.872983346207417f;
  Y[0] = 1.f;
  Y[1] = s3 * y;  Y[2] = s3 * z;  Y[3] = s3 * x;
  Y[4] = s15 * x * y;
  Y[5] = s15 * y * z;
  Y[6] = 0.5f * s5 * (3.f * z * z - 1.f);
  Y[7] = s15 * x * z;
  Y[8] = 0.5f * s15 * (x * x - y * y);
  Y[9]  = 2.091650066335189f * y * (3.f * x * x - y * y);
  Y[10] = 10.246950765959598f * x * y * z;
  Y[11] = 1.6201851746019651f * y * (5.f * z * z - 1.f);
  Y[12] = 1.3228756555322954f * (5.f * z * z * z - 3.f * z);
  Y[13] = 1.6201851746019651f * x * (5.f * z * z - 1.f);
  Y[14] = 5.123475382979799f * (x * x - y * y) * z;
  Y[15] = 2.091650066335189f * x * (x * x - 3.f * y * y);
}

// ---------------- edge geometry: Y, u, cut + degree histogram ----------------
__global__ __launch_bounds__(256) void k_edge_prep(
    const float* __restrict__ pos, const int* __restrict__ esrc,
    const int* __restrict__ edst, float* __restrict__ u_, float* __restrict__ cut_,
    float* __restrict__ Y_, int* __restrict__ cnt) {
  const int e = blockIdx.x * 256 + threadIdx.x;
  if (e >= NE) return;
  const int s = esrc[e], t = edst[e];
  const float ex = pos[t * 3 + 0] - pos[s * 3 + 0];
  const float ey = pos[t * 3 + 1] - pos[s * 3 + 1];
  const float ez = pos[t * 3 + 2] - pos[s * 3 + 2];
  const float d = sqrtf(ex * ex + ey * ey + ez * ez) + 1e-9f;
  const float inv = 1.f / d;
  float Y[16];
  real_sh_f(ex * inv, ey * inv, ez * inv, Y);
#pragma unroll
  for (int c = 0; c < 16; ++c) Y_[(size_t)e * 16 + c] = Y[c];
  const float u = d / 3.5f;
  u_[e] = u;
  cut_[e] = (u < 1.f) ? 0.5f * (cosf(3.14159265358979323846f * u) + 1.f) : 0.f;
  atomicAdd(&cnt[t], 1);
}

// ---------------- CSR build: scan + fill ----------------
__global__ __launch_bounds__(256) void k_scan(const int* __restrict__ cnt,
                                              int* __restrict__ offs,
                                              int* __restrict__ cursor) {
  __shared__ int part[256];
  const int t = threadIdx.x;
  int s = 0;
  for (int i = 0; i < 32; ++i) s += cnt[t * 32 + i];
  part[t] = s;
  __syncthreads();
  if (t == 0) {
    int run = 0;
    for (int i = 0; i < 256; ++i) { int v = part[i]; part[i] = run; run += v; }
    offs[NN] = run;
  }
  __syncthreads();
  int run = part[t];
  for (int i = 0; i < 32; ++i) {
    const int idx = t * 32 + i;
    offs[idx] = run;
    cursor[idx] = run;
    run += cnt[idx];
  }
}

__global__ __launch_bounds__(256) void k_fill(const int* __restrict__ edst,
                                              int* __restrict__ cursor,
                                              int* __restrict__ elist) {
  const int e = blockIdx.x * 256 + threadIdx.x;
  if (e < NE) {
    const int p = atomicAdd(&cursor[edst[e]], 1);
    elist[p] = e;
  }
}

// ---------------- W2^T bf16 hi/lo prep ----------------
template <bool IS2>
__global__ __launch_bounds__(256) void k_prep_w2t(const float* __restrict__ W2,
                                                  ushort* __restrict__ Th,
                                                  ushort* __restrict__ Tl) {
  const int idx = blockIdx.x * 256 + threadIdx.x;
  if (idx >= 128 * 1024) return;
  const int o = idx >> 10, kf = idx & 1023;
  const float v = IS2 ? W2[(size_t)(kf >> 4) * 2176 + (kf & 15) * 128 + o]
                      : W2[(size_t)kf * 128 + o];
  const ushort h = f2bf(v);
  Th[idx] = h;
  Tl[idx] = (ushort)(__float_as_uint(v - bf2f(h)) >> 16);
}

__global__ __launch_bounds__(256) void k_prep_selfw(const float* __restrict__ W2,
                                                    ushort* __restrict__ Sh,
                                                    ushort* __restrict__ Sl) {
  const int idx = blockIdx.x * 256 + threadIdx.x;
  if (idx >= 128 * 64) return;
  const int o = idx >> 6, k = idx & 63;
  const float v = W2[(size_t)k * 2176 + 2048 + o];
  const ushort h = f2bf(v);
  Sh[idx] = h;
  Sl[idx] = (ushort)(__float_as_uint(v - bf2f(h)) >> 16);
}

// ---------------- per-edge bilinear GEMM via split-bf16 MFMA ----------------
// Block: 32 edges (2 m-tiles), 4 waves; wave w owns n-tiles {2w, 2w+1} (N=32).
// Static-named register double-buffer (A/B) — NO runtime-indexed arrays (rule #20).
#define MSG_STEP(HS, BH, BL)                                                     \
  do {                                                                           \
    short8 ah_[2], al_[2];                                                       \
    _Pragma("unroll") for (int mt = 0; mt < 2; ++mt) {                           \
      float p_[8];                                                               \
      _Pragma("unroll") for (int j = 0; j < 8; ++j) p_[j] = HS[mt] * nf8[mt][j]; \
      split8(p_, ah_[mt], al_[mt]);                                              \
    }                                                                            \
    _Pragma("unroll") for (int n = 0; n < 2; ++n) {                              \
      _Pragma("unroll") for (int mt = 0; mt < 2; ++mt) {                         \
        acc[mt][n] = __builtin_amdgcn_mfma_f32_16x16x32_bf16(ah_[mt], BH[n], acc[mt][n], 0, 0, 0); \
        acc[mt][n] = __builtin_amdgcn_mfma_f32_16x16x32_bf16(al_[mt], BH[n], acc[mt][n], 0, 0, 0); \
        acc[mt][n] = __builtin_amdgcn_mfma_f32_16x16x32_bf16(ah_[mt], BL[n], acc[mt][n], 0, 0, 0); \
      }                                                                          \
    }                                                                            \
  } while (0)

template <bool IS2>
__global__ __launch_bounds__(256) void k_msg_mfma(
    const float* __restrict__ u_, const float* __restrict__ cut_,
    const float* __restrict__ W1, const float* __restrict__ bvec,
    const ushort* __restrict__ W2Th, const ushort* __restrict__ W2Tl,
    const ushort* __restrict__ SWh, const ushort* __restrict__ SWl,
    const float* __restrict__ feat16, const int* __restrict__ esrc,
    float* __restrict__ t_, float* __restrict__ self_) {
  __shared__ float hhL[32 * 65];
  __shared__ float nfL[32 * 17];
  __shared__ float uL[32], cL[32];
  __shared__ int sL[32];
  const int tid = threadIdx.x;
  const int e0 = blockIdx.x * 32;
  if (tid < 32) {
    uL[tid] = u_[e0 + tid];
    cL[tid] = cut_[e0 + tid];
    sL[tid] = esrc[e0 + tid];
  }
  __syncthreads();
  for (int i = tid; i < 32 * 64; i += 256) {
    const int e = i >> 6, k = i & 63;
    hhL[e * 65 + k] = fmaxf(fmaf(uL[e], W1[k], bvec[k]), 0.f) * cL[e];
  }
  for (int i = tid; i < 32 * 16; i += 256) {
    const int e = i >> 4, f = i & 15;
    nfL[e * 17 + f] = feat16[(size_t)sL[e] * 16 + f];
  }
  __syncthreads();

  const int lane = tid & 63, wv = tid >> 6;
  const int lr = lane & 15, lg = lane >> 4;
  const int n0 = wv * 2;

  if (IS2) {
    f32x4 sacc[2][2];
#pragma unroll
    for (int mt = 0; mt < 2; ++mt)
#pragma unroll
      for (int n = 0; n < 2; ++n) {
        f32x4 zz = {0.f, 0.f, 0.f, 0.f};
        sacc[mt][n] = zz;
      }
#pragma unroll
    for (int ks2 = 0; ks2 < 2; ++ks2) {
      short8 ash[2], asl[2];
#pragma unroll
      for (int mt = 0; mt < 2; ++mt) {
        float p[8];
        const float* hp = &hhL[(mt * 16 + lr) * 65 + ks2 * 32 + lg * 8];
#pragma unroll
        for (int j = 0; j < 8; ++j) p[j] = hp[j];
        split8(p, ash[mt], asl[mt]);
      }
#pragma unroll
      for (int n = 0; n < 2; ++n) {
        const short8 bh = *(const short8*)&SWh[((n0 + n) * 16 + lr) * 64 + ks2 * 32 + lg * 8];
        const short8 bl = *(const short8*)&SWl[((n0 + n) * 16 + lr) * 64 + ks2 * 32 + lg * 8];
#pragma unroll
        for (int mt = 0; mt < 2; ++mt) {
          sacc[mt][n] = __builtin_amdgcn_mfma_f32_16x16x32_bf16(ash[mt], bh, sacc[mt][n], 0, 0, 0);
          sacc[mt][n] = __builtin_amdgcn_mfma_f32_16x16x32_bf16(asl[mt], bh, sacc[mt][n], 0, 0, 0);
          sacc[mt][n] = __builtin_amdgcn_mfma_f32_16x16x32_bf16(ash[mt], bl, sacc[mt][n], 0, 0, 0);
        }
      }
    }
#pragma unroll
    for (int mt = 0; mt < 2; ++mt)
#pragma unroll
      for (int n = 0; n < 2; ++n)
#pragma unroll
        for (int i = 0; i < 4; ++i)
          self_[(size_t)(e0 + mt * 16 + lg * 4 + i) * 128 + (n0 + n) * 16 + lr] =
              sacc[mt][n][i] * 0.5f;
  }

  float nf8[2][8];
#pragma unroll
  for (int mt = 0; mt < 2; ++mt)
#pragma unroll
    for (int j = 0; j < 8; ++j)
      nf8[mt][j] = nfL[(mt * 16 + lr) * 17 + (lg & 1) * 8 + j];

  f32x4 acc[2][2];
#pragma unroll
  for (int mt = 0; mt < 2; ++mt)
#pragma unroll
    for (int n = 0; n < 2; ++n) {
      f32x4 zz = {0.f, 0.f, 0.f, 0.f};
      acc[mt][n] = zz;
    }

  const ushort* bh_base[2] = {
    &W2Th[(size_t)((n0 + 0) * 16 + lr) * 1024 + lg * 8],
    &W2Th[(size_t)((n0 + 1) * 16 + lr) * 1024 + lg * 8]};
  const ushort* bl_base[2] = {
    &W2Tl[(size_t)((n0 + 0) * 16 + lr) * 1024 + lg * 8],
    &W2Tl[(size_t)((n0 + 1) * 16 + lr) * 1024 + lg * 8]};
  const float* hs_base[2] = {&hhL[(0 * 16 + lr) * 65 + (lg >> 1)],
                             &hhL[(1 * 16 + lr) * 65 + (lg >> 1)]};

  // static double-buffer: A holds even ks, B holds odd ks
  short8 bhA[2], blA[2], bhB[2], blB[2];
  float hsA[2], hsB[2];
#pragma unroll
  for (int n = 0; n < 2; ++n) {
    bhA[n] = *(const short8*)(bh_base[n]);
    blA[n] = *(const short8*)(bl_base[n]);
  }
  hsA[0] = hs_base[0][0];
  hsA[1] = hs_base[1][0];

  for (int ks = 0; ks < 32; ks += 2) {
    // prefetch ks+1 into B
#pragma unroll
    for (int n = 0; n < 2; ++n) {
      bhB[n] = *(const short8*)(bh_base[n] + (ks + 1) * 32);
      blB[n] = *(const short8*)(bl_base[n] + (ks + 1) * 32);
    }
    hsB[0] = hs_base[0][2 * (ks + 1)];
    hsB[1] = hs_base[1][2 * (ks + 1)];
    // compute ks (A)
    MSG_STEP(hsA, bhA, blA);
    // prefetch ks+2 into A
    if (ks + 2 < 32) {
#pragma unroll
      for (int n = 0; n < 2; ++n) {
        bhA[n] = *(const short8*)(bh_base[n] + (ks + 2) * 32);
        blA[n] = *(const short8*)(bl_base[n] + (ks + 2) * 32);
      }
      hsA[0] = hs_base[0][2 * (ks + 2)];
      hsA[1] = hs_base[1][2 * (ks + 2)];
    }
    // compute ks+1 (B)
    MSG_STEP(hsB, bhB, blB);
  }
#pragma unroll
  for (int mt = 0; mt < 2; ++mt)
#pragma unroll
    for (int n = 0; n < 2; ++n)
#pragma unroll
      for (int i = 0; i < 4; ++i)
        t_[(size_t)(e0 + mt * 16 + lg * 4 + i) * 128 + (n0 + n) * 16 + lr] =
            acc[mt][n][i] * 0.125f;  // 1/sqrt(F)/deg
}

// ---------------- gather (segment sum over incoming edges) + gate ----------------
__global__ __launch_bounds__(256) void k_gather1(
    const float* __restrict__ t_, const float* __restrict__ Y_,
    const int* __restrict__ offs, const int* __restrict__ elist,
    float* __restrict__ h1, float* __restrict__ h1s) {
  __shared__ float tL[128], YL[16], sG[32];
  const int n = blockIdx.x, tid = threadIdx.x;
  const int beg = offs[n], end = offs[n + 1];
  const int cc = tid & 15;
  const int lx = lidx_of(cc);
  const int o0 = ((tid >> 4) << 2) + lx;
  const int o1 = o0 + 64;
  float a0 = 0.f, a1 = 0.f;
  for (int ei = beg; ei < end; ++ei) {
    const int e = elist[ei];
    __syncthreads();
    if (tid < 128) tL[tid] = t_[(size_t)e * 128 + tid];
    else if (tid < 144) YL[tid - 128] = Y_[(size_t)e * 16 + tid - 128];
    __syncthreads();
    const float yv = YL[cc];
    a0 = fmaf(tL[o0], yv, a0);
    a1 = fmaf(tL[o1], yv, a1);
  }
  if (cc == 0) { sG[tid >> 4] = a0; sG[(tid >> 4) + 16] = a1; }
  __syncthreads();
  const float s0 = sG[tid >> 4], s1 = sG[(tid >> 4) + 16];
  const float r0 = (cc == 0) ? fmaxf(a0, 0.f) : a0 * (1.f / (1.f + expf(-s0)));
  const float r1 = (cc == 0) ? fmaxf(a1, 0.f) : a1 * (1.f / (1.f + expf(-s1)));
  h1[(size_t)n * 512 + tid] = r0;
  h1[(size_t)n * 512 + tid + 256] = r1;
  if ((tid & 31) == 0) {
    h1s[n * 16 + (tid >> 5)] = r0;
    h1s[n * 16 + (tid >> 5) + 8] = r1;
  }
}

__global__ __launch_bounds__(256) void k_gather2(
    const float* __restrict__ t_, const float* __restrict__ self_,
    const float* __restrict__ Y_, const float* __restrict__ h1,
    const int* __restrict__ offs, const int* __restrict__ elist,
    const int* __restrict__ esrc, float* __restrict__ h2) {
  __shared__ float tL[128], wL[128], YL[16], sG[32];
  const int n = blockIdx.x, tid = threadIdx.x;
  const int beg = offs[n], end = offs[n + 1];
  const int cc = tid & 15;
  const int lx = lidx_of(cc);
  const int o0 = ((tid >> 4) << 2) + lx;
  const int o1 = o0 + 64;
  float a0 = 0.f, a1 = 0.f;
  for (int ei = beg; ei < end; ++ei) {
    const int e = elist[ei];
    __syncthreads();
    if (tid < 128) tL[tid] = t_[(size_t)e * 128 + tid];
    else wL[tid - 128] = self_[(size_t)e * 128 + tid - 128];
    if (tid < 16) YL[tid] = Y_[(size_t)e * 16 + tid];
    __syncthreads();
    const int src = esrc[e];
    const float* hr = &h1[(size_t)src * 512];
    const float yv = YL[cc];
    a0 += tL[o0] * yv + hr[tid] * wL[o0];
    a1 += tL[o1] * yv + hr[tid + 256] * wL[o1];
  }
  if (cc == 0) { sG[tid >> 4] = a0; sG[(tid >> 4) + 16] = a1; }
  __syncthreads();
  const float s0 = sG[tid >> 4], s1 = sG[(tid >> 4) + 16];
  const float r0 = (cc == 0) ? fmaxf(a0, 0.f) : a0 * (1.f / (1.f + expf(-s0)));
  const float r1 = (cc == 0) ? fmaxf(a1, 0.f) : a1 * (1.f / (1.f + expf(-s1)));
  h2[(size_t)n * 512 + tid] = r0;
  h2[(size_t)n * 512 + tid + 256] = r1;
}

// ---------------- mean pool over each graph's 256 nodes ----------------
__global__ __launch_bounds__(256) void k_pool(const float* __restrict__ h2,
                                              float* __restrict__ enc) {
  const int b = blockIdx.x, tid = threadIdx.x;
  float a0 = 0.f, a1 = 0.f;
  for (int i = 0; i < 256; ++i) {
    const float* row = &h2[(size_t)(b * 256 + i) * 512];
    a0 += row[tid];
    a1 += row[tid + 256];
  }
  enc[b * 512 + tid] = a0 * (1.f / 256.f);
  enc[b * 512 + tid + 256] = a1 * (1.f / 256.f);
}

// ---------------- z = per-l linear mix of enc (B,32,16) -> (B,16,84) ----------------
__global__ __launch_bounds__(256) void k_zproj(const float* __restrict__ enc,
                                               const float* __restrict__ Wlin,
                                               float* __restrict__ z) {
  __shared__ float eL[512];
  const int b = blockIdx.x, tid = threadIdx.x;
  eL[tid] = enc[b * 512 + tid];
  eL[tid + 256] = enc[b * 512 + tid + 256];
  __syncthreads();
  for (int idx = tid; idx < 16 * 84; idx += 256) {
    const int g = idx / 84, d3 = idx % 84;
    int o0, m0, mo;
    if (d3 < 1)       { o0 = 0;  m0 = 1; mo = 0; }
    else if (d3 < 10) { o0 = 1;  m0 = 3; mo = 1; }
    else if (d3 < 35) { o0 = 10; m0 = 5; mo = 4; }
    else              { o0 = 35; m0 = 7; mo = 9; }
    const int rem = d3 - o0;
    const int jj = rem / m0;
    const int cc2 = rem - jj * m0;
    float a = 0.f;
    for (int mu = 0; mu < 32; ++mu)
      a = fmaf(eL[mu * 16 + mo + cc2], Wlin[(mu * 16 + g) * 16 + mo + jj], a);
    z[(size_t)(b * 16 + g) * 84 + d3] = a * 0.17677669529663687f;  // 1/sqrt(32)
  }
}

// ---------------- SO3 conv as split-bf16 MFMA GEMMs ----------------
template <int FI>
__global__ __launch_bounds__(256) void k_prep_xg(const float* __restrict__ x,
                                                 ushort* __restrict__ Xh,
                                                 ushort* __restrict__ Xl) {
  constexpr int KP0 = (FI + 31) & ~31, KP1 = (3 * FI + 31) & ~31;
  constexpr int KP2 = (5 * FI + 31) & ~31, KP3 = (7 * FI + 31) & ~31;
  constexpr int XO1 = 32 * KP0, XO2 = XO1 + 96 * KP1, XO3 = XO2 + 160 * KP2;
  constexpr int TOT = XO3 + 224 * KP3;
  const int idx = blockIdx.x * 256 + threadIdx.x;
  if (idx >= TOT) return;
  int m, o0, base, KP;
  if (idx < XO1)      { m = 1; o0 = 0;  base = 0;   KP = KP0; }
  else if (idx < XO2) { m = 3; o0 = 1;  base = XO1; KP = KP1; }
  else if (idx < XO3) { m = 5; o0 = 10; base = XO2; KP = KP2; }
  else                { m = 7; o0 = 35; base = XO3; KP = KP3; }
  const int rel = idx - base;
  const int r = rel / KP, k = rel % KP;
  ushort h = 0, lo = 0;
  if (k < FI * m) {
    const int f = k / m, i = k % m, b = r / m, c = r % m;
    const float v = x[((size_t)b * FI + f) * 84 + o0 + i * m + c];
    h = f2bf(v);
    lo = (ushort)(__float_as_uint(v - bf2f(h)) >> 16);
  }
  Xh[idx] = h;
  Xl[idx] = lo;
}

template <int FI, int FO>
__global__ __launch_bounds__(256) void k_prep_psig(const float* __restrict__ psi,
                                                   ushort* __restrict__ Ph,
                                                   ushort* __restrict__ Pl) {
  constexpr int KP0 = (FI + 31) & ~31, KP1 = (3 * FI + 31) & ~31;
  constexpr int KP2 = (5 * FI + 31) & ~31, KP3 = (7 * FI + 31) & ~31;
  constexpr int PO1 = FO * KP0, PO2 = PO1 + 3 * FO * KP1, PO3 = PO2 + 5 * FO * KP2;
  constexpr int TOT = PO3 + 7 * FO * KP3;
  const int idx = blockIdx.x * 256 + threadIdx.x;
  if (idx >= TOT) return;
  int m, o0, base, KP;
  if (idx < PO1)      { m = 1; o0 = 0;  base = 0;   KP = KP0; }
  else if (idx < PO2) { m = 3; o0 = 1;  base = PO1; KP = KP1; }
  else if (idx < PO3) { m = 5; o0 = 10; base = PO2; KP = KP2; }
  else                { m = 7; o0 = 35; base = PO3; KP = KP3; }
  const int rel = idx - base;
  const int n = rel / KP, k = rel % KP;
  ushort h = 0, lo = 0;
  if (k < FI * m) {
    const int f = k / m, i = k % m, g = n / m, j = n % m;
    const float v = psi[((size_t)f * FO + g) * 84 + o0 + i * m + j];
    h = f2bf(v);
    lo = (ushort)(__float_as_uint(v - bf2f(h)) >> 16);
  }
  Ph[idx] = h;
  Pl[idx] = lo;
}

template <int FI, int FO>
__global__ __launch_bounds__(256) void k_conv_gemm(
    const ushort* __restrict__ Xh, const ushort* __restrict__ Xl,
    const ushort* __restrict__ Ph, const ushort* __restrict__ Pl,
    float* __restrict__ out) {
  constexpr int KP0 = (FI + 31) & ~31, KP1 = (3 * FI + 31) & ~31;
  constexpr int KP2 = (5 * FI + 31) & ~31, KP3 = (7 * FI + 31) & ~31;
  constexpr int XO1 = 32 * KP0, XO2 = XO1 + 96 * KP1, XO3 = XO2 + 160 * KP2;
  constexpr int PO1 = FO * KP0, PO2 = PO1 + 3 * FO * KP1, PO3 = PO2 + 5 * FO * KP2;
  constexpr int NT0 = 1 * (FO / 32), NT1 = 3 * (3 * FO / 32);
  constexpr int NT2 = 5 * (5 * FO / 32), NT3 = 7 * (7 * FO / 32);
  constexpr int TB1 = NT0, TB2 = TB1 + NT1, TB3 = TB2 + NT2, TOT = TB3 + NT3;

  const int wt = blockIdx.x * 4 + (threadIdx.x >> 6);
  if (wt >= TOT) return;
  int m, o0, Mt, KP, Xo, Po, loc;
  if (wt < TB1)      { m = 1; o0 = 0;  Mt = 1; KP = KP0; Xo = 0;   Po = 0;   loc = wt; }
  else if (wt < TB2) { m = 3; o0 = 1;  Mt = 3; KP = KP1; Xo = XO1; Po = PO1; loc = wt - TB1; }
  else if (wt < TB3) { m = 5; o0 = 10; Mt = 5; KP = KP2; Xo = XO2; Po = PO2; loc = wt - TB2; }
  else               { m = 7; o0 = 35; Mt = 7; KP = KP3; Xo = XO3; Po = PO3; loc = wt - TB3; }
  const int mt0 = (loc % Mt) * 32;
  const int nt0 = (loc / Mt) * 32;
  const int lane = threadIdx.x & 63, lr = lane & 15, lg = lane >> 4;

  f32x4 acc[2][2];
#pragma unroll
  for (int mt = 0; mt < 2; ++mt)
#pragma unroll
    for (int nt = 0; nt < 2; ++nt) {
      f32x4 zz = {0.f, 0.f, 0.f, 0.f};
      acc[mt][nt] = zz;
    }

  const int nks = KP >> 5;
  for (int ks = 0; ks < nks; ++ks) {
    short8 ah[2], al[2], bh[2], bl[2];
#pragma unroll
    for (int t = 0; t < 2; ++t) {
      const size_t xa = (size_t)Xo + (size_t)(mt0 + t * 16 + lr) * KP + ks * 32 + lg * 8;
      ah[t] = *(const short8*)&Xh[xa];
      al[t] = *(const short8*)&Xl[xa];
      const size_t pa = (size_t)Po + (size_t)(nt0 + t * 16 + lr) * KP + ks * 32 + lg * 8;
      bh[t] = *(const short8*)&Ph[pa];
      bl[t] = *(const short8*)&Pl[pa];
    }
#pragma unroll
    for (int nt = 0; nt < 2; ++nt)
#pragma unroll
      for (int mt = 0; mt < 2; ++mt) {
        acc[mt][nt] = __builtin_amdgcn_mfma_f32_16x16x32_bf16(ah[mt], bh[nt], acc[mt][nt], 0, 0, 0);
        acc[mt][nt] = __builtin_amdgcn_mfma_f32_16x16x32_bf16(al[mt], bh[nt], acc[mt][nt], 0, 0, 0);
        acc[mt][nt] = __builtin_amdgcn_mfma_f32_16x16x32_bf16(ah[mt], bl[nt], acc[mt][nt], 0, 0, 0);
      }
  }

  const float scale = 1.f / sqrtf((float)(FI * m));
#pragma unroll
  for (int mt = 0; mt < 2; ++mt)
#pragma unroll
    for (int nt = 0; nt < 2; ++nt)
#pragma unroll
      for (int i = 0; i < 4; ++i) {
        const int R = mt0 + mt * 16 + lg * 4 + i;
        const int C2 = nt0 + nt * 16 + lr;
        const int b = R / m, c = R - b * m;
        const int g = C2 / m, j = C2 - g * m;
        out[((size_t)b * FO + g) * 84 + o0 + j * m + c] = acc[mt][nt][i] * scale;
      }
}

// ---------------- weight prep for MFMA act ----------------
__global__ __launch_bounds__(256) void k_prep_gt(const float* __restrict__ Gt,
                                                 ushort* __restrict__ GtT) {
  const int idx = blockIdx.x * 256 + threadIdx.x;
  if (idx >= 4096 * 96) return;
  const int g = idx / 96, k = idx % 96;
  GtT[idx] = (k < 84) ? f2bf(Gt[(size_t)k * 4096 + g]) : (ushort)0;
}
__global__ __launch_bounds__(256) void k_prep_gf(const float* __restrict__ Gf,
                                                 ushort* __restrict__ GfT) {
  const int idx = blockIdx.x * 256 + threadIdx.x;
  if (idx >= 96 * 4096) return;
  const int d = idx / 4096, g = idx % 4096;
  GfT[idx] = (d < 84) ? f2bf(Gf[(size_t)g * 84 + d]) : (ushort)0;
}
__global__ __launch_bounds__(256) void k_cvtx(const float* __restrict__ x,
                                              ushort* __restrict__ Xb, int total) {
  const int idx = blockIdx.x * 256 + threadIdx.x;
  if (idx >= total) return;
  const int r = idx / 96, k = idx % 96;
  Xb[idx] = (k < 84) ? f2bf(x[(size_t)r * 84 + k]) : (ushort)0;
}

// ---------------- SO3 act via bf16 MFMA (fused, g-split partials) ----------------
template <int GS>
__global__ __launch_bounds__(256) void k_act_mfma(
    const ushort* __restrict__ Xb, const ushort* __restrict__ GtT,
    const ushort* __restrict__ GfT, float* __restrict__ part, int NR) {
  constexpr int CPB = 64 / GS;
  __shared__ __align__(16) ushort ldsGt[64 * 104];
  __shared__ __align__(16) ushort ldsH[128 * 72];
  __shared__ __align__(16) ushort ldsGf[96 * 72];
  const int tid = threadIdx.x;
  const int gs = blockIdx.x;
  const int row0 = blockIdx.y * 128;
  const int lane = tid & 63, wv = tid >> 6;
  const int lr = lane & 15, lg = lane >> 4;
  const int m0 = wv * 32;

  short8 a1[2][3];
#pragma unroll
  for (int mt = 0; mt < 2; ++mt)
#pragma unroll
    for (int ks = 0; ks < 3; ++ks)
      a1[mt][ks] = *(const short8*)&Xb[(size_t)(row0 + m0 + mt * 16 + lr) * 96 +
                                       ks * 32 + lg * 8];

  f32x4 acc2[6][2];
#pragma unroll
  for (int m2 = 0; m2 < 6; ++m2)
#pragma unroll
    for (int n2 = 0; n2 < 2; ++n2) {
      f32x4 zz = {0.f, 0.f, 0.f, 0.f};
      acc2[m2][n2] = zz;
    }

  for (int ch = gs * CPB; ch < (gs + 1) * CPB; ++ch) {
    const int g0 = ch * 64;
    __syncthreads();
    for (int i = tid; i < 768; i += 256) {
      const int row = i / 12, c = i % 12;
      *(uint4*)&ldsGt[row * 104 + c * 8] =
          *(const uint4*)&GtT[(size_t)(g0 + row) * 96 + c * 8];
    }
    for (int i = tid; i < 768; i += 256) {
      const int row = i / 8, c = i % 8;
      *(uint4*)&ldsGf[row * 72 + c * 8] =
          *(const uint4*)&GfT[(size_t)row * 4096 + g0 + c * 8];
    }
    __syncthreads();
#pragma unroll
    for (int n = 0; n < 4; ++n) {
      short8 b[3];
#pragma unroll
      for (int ks = 0; ks < 3; ++ks)
        b[ks] = *(const short8*)&ldsGt[(n * 16 + lr) * 104 + ks * 32 + lg * 8];
#pragma unroll
      for (int mt = 0; mt < 2; ++mt) {
        f32x4 c1 = {0.f, 0.f, 0.f, 0.f};
#pragma unroll
        for (int ks = 0; ks < 3; ++ks)
          c1 = __builtin_amdgcn_mfma_f32_16x16x32_bf16(a1[mt][ks], b[ks], c1, 0, 0, 0);
        ushort* hp = &ldsH[(m0 + mt * 16 + lg * 4) * 72 + n * 16 + lr];
#pragma unroll
        for (int i = 0; i < 4; ++i) hp[i * 72] = f2bf(fmaxf(c1[i], 0.f));
      }
    }
#pragma unroll
    for (int k2 = 0; k2 < 2; ++k2) {
      short8 bh[2];
#pragma unroll
      for (int n2 = 0; n2 < 2; ++n2)
        bh[n2] = *(const short8*)&ldsH[(m0 + n2 * 16 + lr) * 72 + k2 * 32 + lg * 8];
#pragma unroll
      for (int m2 = 0; m2 < 6; ++m2) {
        const short8 a2 = *(const short8*)&ldsGf[(m2 * 16 + lr) * 72 + k2 * 32 + lg * 8];
        acc2[m2][0] = __builtin_amdgcn_mfma_f32_16x16x32_bf16(a2, bh[0], acc2[m2][0], 0, 0, 0);
        acc2[m2][1] = __builtin_amdgcn_mfma_f32_16x16x32_bf16(a2, bh[1], acc2[m2][1], 0, 0, 0);
      }
    }
  }
#pragma unroll
  for (int m2 = 0; m2 < 6; ++m2)
#pragma unroll
    for (int n2 = 0; n2 < 2; ++n2)
#pragma unroll
      for (int i = 0; i < 4; ++i) {
        const int d = m2 * 16 + lg * 4 + i;
        if (d < 84) {
          const int r = row0 + m0 + n2 * 16 + lr;
          part[((size_t)gs * NR + r) * 84 + d] = acc2[m2][n2][i];
        }
      }
}

template <int GS>
__global__ __launch_bounds__(256) void k_act_reduce(const float* __restrict__ part,
                                                    float* __restrict__ out, int total) {
  const int i = blockIdx.x * 256 + threadIdx.x;
  if (i < total) {
    float s = part[i];
#pragma unroll
    for (int g = 1; g < GS; ++g) s += part[(size_t)g * total + i];
    out[i] = s * (1.f / (9.16515138991168f * 64.f));
  }
}

// ---------------- final: Ws2 contraction + orientation SH dot ----------------
__global__ __launch_bounds__(256) void k_final(const float* __restrict__ x,
                                               const float* __restrict__ Ws2,
                                               const float* __restrict__ orient,
                                               float* __restrict__ outp) {
  __shared__ float red[256][16];
  const int b = blockIdx.x, tid = threadIdx.x;
  const float* xr = &x[(size_t)(b * 256 + tid) * 84];
  const float* wr = &Ws2[tid * 16];
  float acc[16];
#pragma unroll
  for (int c = 0; c < 16; ++c) acc[c] = 0.f;
  acc[0] = fmaf(xr[0], wr[0], acc[0]);
#pragma unroll
  for (int i = 0; i < 3; ++i) {
    const float w = wr[1 + i];
#pragma unroll
    for (int c = 0; c < 3; ++c) acc[1 + c] = fmaf(xr[1 + i * 3 + c], w, acc[1 + c]);
  }
#pragma unroll
  for (int i = 0; i < 5; ++i) {
    const float w = wr[4 + i];
#pragma unroll
    for (int c = 0; c < 5; ++c) acc[4 + c] = fmaf(xr[10 + i * 5 + c], w, acc[4 + c]);
  }
#pragma unroll
  for (int i = 0; i < 7; ++i) {
    const float w = wr[9 + i];
#pragma unroll
    for (int c = 0; c < 7; ++c) acc[9 + c] = fmaf(xr[35 + i * 7 + c], w, acc[9 + c]);
  }
#pragma unroll
  for (int c = 0; c < 16; ++c) red[tid][c] = acc[c];
  __syncthreads();
  for (int off = 128; off > 0; off >>= 1) {
    if (tid < off)
#pragma unroll
      for (int c = 0; c < 16; ++c) red[tid][c] += red[tid + off][c];
    __syncthreads();
  }
  if (tid == 0) {
    const float aa = orient[b * 2 + 0], rr = orient[b * 2 + 1];
    float Y[16];
    real_sh_f(-sinf(aa) * cosf(rr), -sinf(aa) * sinf(rr), -cosf(aa), Y);
    const float sc1 = 1.f / 16.f;
    const float sc3 = 1.f / (16.f * 1.7320508075688772f);
    const float sc5 = 1.f / (16.f * 2.23606797749979f);
    const float sc7 = 1.f / (16.f * 2.6457513110645907f);
    float o = red[0][0] * sc1 * Y[0];
#pragma unroll
    for (int c = 1; c < 4; ++c) o += red[0][c] * sc3 * Y[c];
#pragma unroll
    for (int c = 4; c < 9; ++c) o += red[0][c] * sc5 * Y[c];
#pragma unroll
    for (int c = 9; c < 16; ++c) o += red[0][c] * sc7 * Y[c];
    outp[b] = o;
  }
}

extern "C" void kernel_launch(void* const* d_in, const int* in_sizes, int n_in,
                              void* d_out, int out_size, void* d_ws, size_t ws_size,
                              hipStream_t stream) {
  const float* node_feat = (const float*)d_in[0];
  const float* pos       = (const float*)d_in[1];
  const float* orient    = (const float*)d_in[2];
  const float* rad1_W1   = (const float*)d_in[3];
  const float* rad1_b    = (const float*)d_in[4];
  const float* rad1_W2   = (const float*)d_in[5];
  const float* rad2_W1   = (const float*)d_in[6];
  const float* rad2_b    = (const float*)d_in[7];
  const float* rad2_W2   = (const float*)d_in[8];
  const float* Wlin      = (const float*)d_in[9];
  const float* psi1      = (const float*)d_in[10];
  const float* psi2      = (const float*)d_in[11];
  const float* psi3      = (const float*)d_in[12];
  const float* G_to      = (const float*)d_in[13];
  const float* G_from    = (const float*)d_in[14];
  const float* Ws2       = (const float*)d_in[15];
  const int*   esrc      = (const int*)d_in[16];
  const int*   edst      = (const int*)d_in[17];

  float* w = (float*)d_ws;
  size_t off = 0;
  float* u_    = w + off; off += NE;
  float* cut_  = w + off; off += NE;
  float* Y_    = w + off; off += (size_t)NE * 16;   // later: Xp hi/lo (bf16)
  float* t_    = w + off; off += (size_t)NE * 128;  // t1/t2; later act partials
  float* self_ = w + off; off += (size_t)NE * 128;
  float* h1    = w + off; off += (size_t)NN * 512;  // later: GtT/GfT/Xb (bf16)
  float* h1s   = w + off; off += (size_t)NN * 16;
  float* h2    = w + off; off += (size_t)NN * 512;  // later: Psi-p hi/lo (bf16)
  float* enc   = w + off; off += (size_t)NB * 512;
  float* z     = w + off; off += (size_t)NB * 16 * 84;
  float* xb1   = w + off; off += (size_t)NB * 256 * 84;
  float* xb2   = w + off; off += (size_t)NB * 256 * 84;
  int* cnt    = (int*)(w + off); off += NN;
  int* offs   = (int*)(w + off); off += NN + 1;
  int* cursor = (int*)(w + off); off += NN;
  int* elist  = (int*)(w + off); off += NE;
  ushort* W2Th = (ushort*)(w + off); off += 65536;
  ushort* W2Tl = (ushort*)(w + off); off += 65536;
  ushort* SWh  = (ushort*)(w + off); off += 4096;
  ushort* SWl  = (ushort*)(w + off); off += 4096;

  // reuse of dead buffers during conv/act chain:
  float* part = t_;
  ushort* GtT = (ushort*)h1;
  ushort* GfT = GtT + 4096 * 96;
  ushort* Xb  = GfT + 96 * 4096;
  ushort* Xph = (ushort*)Y_;
  ushort* Xpl = Xph + 344064;
  ushort* Pph = (ushort*)h2;
  ushort* Ppl = Pph + 2752512;

  hipMemsetAsync(cnt, 0, NN * sizeof(int), stream);
  k_edge_prep<<<NE / 256, 256, 0, stream>>>(pos, esrc, edst, u_, cut_, Y_, cnt);
  k_scan<<<1, 256, 0, stream>>>(cnt, offs, cursor);
  k_fill<<<NE / 256, 256, 0, stream>>>(edst, cursor, elist);

  k_prep_w2t<false><<<512, 256, 0, stream>>>(rad1_W2, W2Th, W2Tl);
  k_msg_mfma<false><<<NE / 32, 256, 0, stream>>>(u_, cut_, rad1_W1, rad1_b, W2Th, W2Tl,
                                                 nullptr, nullptr, node_feat, esrc,
                                                 t_, nullptr);
  k_gather1<<<NN, 256, 0, stream>>>(t_, Y_, offs, elist, h1, h1s);

  k_prep_w2t<true><<<512, 256, 0, stream>>>(rad2_W2, W2Th, W2Tl);
  k_prep_selfw<<<32, 256, 0, stream>>>(rad2_W2, SWh, SWl);
  k_msg_mfma<true><<<NE / 32, 256, 0, stream>>>(u_, cut_, rad2_W1, rad2_b, W2Th, W2Tl,
                                                SWh, SWl, h1s, esrc, t_, self_);
  k_gather2<<<NN, 256, 0, stream>>>(t_, self_, Y_, h1, offs, elist, esrc, h2);
  k_pool<<<NB, 256, 0, stream>>>(h2, enc);
  k_zproj<<<NB, 256, 0, stream>>>(enc, Wlin, z);

  k_prep_gt<<<(4096 * 96 + 255) / 256, 256, 0, stream>>>(G_to, GtT);
  k_prep_gf<<<(96 * 4096 + 255) / 256, 256, 0, stream>>>(G_from, GfT);

  // ---- stage 1
  k_prep_psig<16, 64><<<(102400 + 255) / 256, 256, 0, stream>>>(psi1, Pph, Ppl);
  k_prep_xg<16><<<(51200 + 255) / 256, 256, 0, stream>>>(z, Xph, Xpl);
  k_conv_gemm<16, 64><<<42, 256, 0, stream>>>(Xph, Xpl, Pph, Ppl, xb1);
  k_cvtx<<<(2048 * 96 + 255) / 256, 256, 0, stream>>>(xb1, Xb, 2048 * 96);
  k_act_mfma<32><<<dim3(32, 16), 256, 0, stream>>>(Xb, GtT, GfT, part, 2048);
  k_act_reduce<32><<<(2048 * 84 + 255) / 256, 256, 0, stream>>>(part, xb2, 2048 * 84);

  // ---- stage 2
  k_prep_psig<64, 128><<<(688128 + 255) / 256, 256, 0, stream>>>(psi2, Pph, Ppl);
  k_prep_xg<64><<<(172032 + 255) / 256, 256, 0, stream>>>(xb2, Xph, Xpl);
  k_conv_gemm<64, 128><<<84, 256, 0, stream>>>(Xph, Xpl, Pph, Ppl, xb1);
  k_cvtx<<<(4096 * 96 + 255) / 256, 256, 0, stream>>>(xb1, Xb, 4096 * 96);
  k_act_mfma<16><<<dim3(16, 32), 256, 0, stream>>>(Xb, GtT, GfT, part, 4096);
  k_act_reduce<16><<<(4096 * 84 + 255) / 256, 256, 0, stream>>>(part, xb2, 4096 * 84);

  // ---- stage 3
  k_prep_psig<128, 256><<<(2752512 + 255) / 256, 256, 0, stream>>>(psi3, Pph, Ppl);
  k_prep_xg<128><<<(344064 + 255) / 256, 256, 0, stream>>>(xb2, Xph, Xpl);
  k_conv_gemm<128, 256><<<168, 256, 0, stream>>>(Xph, Xpl, Pph, Ppl, xb1);
  k_cvtx<<<(8192 * 96 + 255) / 256, 256, 0, stream>>>(xb1, Xb, 8192 * 96);
  k_act_mfma<8><<<dim3(8, 64), 256, 0, stream>>>(Xb, GtT, GfT, part, 8192);
  k_act_reduce<8><<<(8192 * 84 + 255) / 256, 256, 0, stream>>>(part, xb2, 8192 * 84);

  k_final<<<NB, 256, 0, stream>>>(xb2, Ws2, orient, (float*)d_out);
}

// Round 12
// 383.173 us; speedup vs baseline: 3.9883x; 1.1197x over previous
//
#include <hip/hip_runtime.h>
#include <math.h>

#define DEV static __device__ __forceinline__

constexpr int NN = 8192;    // nodes
constexpr int NE = 32768;   // edges
constexpr int NB = 32;      // graphs

using short8 = __attribute__((ext_vector_type(8))) short;
using half8  = __attribute__((ext_vector_type(8))) _Float16;
using f32x4  = __attribute__((ext_vector_type(4))) float;

DEV ushort f2bf(float f) {  // round-to-nearest-even f32 -> bf16 bits
  unsigned u = __float_as_uint(f);
  unsigned r = (u + 0x7FFFu + ((u >> 16) & 1u)) >> 16;
  return (ushort)r;
}
DEV float bf2f(ushort h) { return __uint_as_float(((unsigned)h) << 16); }

// split p[8] into fp16 hi + fp16 residual (RNE cvt; residual catches the error)
DEV void split8h(const float* p, half8& hi, half8& lo) {
#pragma unroll
  for (int j = 0; j < 8; ++j) {
    const _Float16 h = (_Float16)p[j];
    hi[j] = h;
    lo[j] = (_Float16)(p[j] - (float)h);
  }
}

DEV int lidx_of(int c) { return (c == 0) ? 0 : (c < 4) ? 1 : (c < 9) ? 2 : 3; }

DEV void real_sh_f(float x, float y, float z, float* Y) {
  const float s3  = 1.7320508075688772f;
  const float s5  = 2.23606797749979f;
  const float s15 = 3.872983346207417f;
  Y[0] = 1.f;
  Y[1] = s3 * y;  Y[2] = s3 * z;  Y[3] = s3 * x;
  Y[4] = s15 * x * y;
  Y[5] = s15 * y * z;
  Y[6] = 0.5f * s5 * (3.f * z * z - 1.f);
  Y[7] = s15 * x * z;
  Y[8] = 0.5f * s15 * (x * x - y * y);
  Y[9]  = 2.091650066335189f * y * (3.f * x * x - y * y);
  Y[10] = 10.246950765959598f * x * y * z;
  Y[11] = 1.6201851746019651f * y * (5.f * z * z - 1.f);
  Y[12] = 1.3228756555322954f * (5.f * z * z * z - 3.f * z);
  Y[13] = 1.6201851746019651f * x * (5.f * z * z - 1.f);
  Y[14] = 5.123475382979799f * (x * x - y * y) * z;
  Y[15] = 2.091650066335189f * x * (x * x - 3.f * y * y);
}

// ---------------- edge geometry: Y, u, cut + degree histogram ----------------
__global__ __launch_bounds__(256) void k_edge_prep(
    const float* __restrict__ pos, const int* __restrict__ esrc,
    const int* __restrict__ edst, float* __restrict__ u_, float* __restrict__ cut_,
    float* __restrict__ Y_, int* __restrict__ cnt) {
  const int e = blockIdx.x * 256 + threadIdx.x;
  if (e >= NE) return;
  const int s = esrc[e], t = edst[e];
  const float ex = pos[t * 3 + 0] - pos[s * 3 + 0];
  const float ey = pos[t * 3 + 1] - pos[s * 3 + 1];
  const float ez = pos[t * 3 + 2] - pos[s * 3 + 2];
  const float d = sqrtf(ex * ex + ey * ey + ez * ez) + 1e-9f;
  const float inv = 1.f / d;
  float Y[16];
  real_sh_f(ex * inv, ey * inv, ez * inv, Y);
#pragma unroll
  for (int c = 0; c < 16; ++c) Y_[(size_t)e * 16 + c] = Y[c];
  const float u = d / 3.5f;
  u_[e] = u;
  cut_[e] = (u < 1.f) ? 0.5f * (cosf(3.14159265358979323846f * u) + 1.f) : 0.f;
  atomicAdd(&cnt[t], 1);
}

// ---------------- CSR build: scan + fill ----------------
__global__ __launch_bounds__(256) void k_scan(const int* __restrict__ cnt,
                                              int* __restrict__ offs,
                                              int* __restrict__ cursor) {
  __shared__ int part[256];
  const int t = threadIdx.x;
  int s = 0;
  for (int i = 0; i < 32; ++i) s += cnt[t * 32 + i];
  part[t] = s;
  __syncthreads();
  if (t == 0) {
    int run = 0;
    for (int i = 0; i < 256; ++i) { int v = part[i]; part[i] = run; run += v; }
    offs[NN] = run;
  }
  __syncthreads();
  int run = part[t];
  for (int i = 0; i < 32; ++i) {
    const int idx = t * 32 + i;
    offs[idx] = run;
    cursor[idx] = run;
    run += cnt[idx];
  }
}

__global__ __launch_bounds__(256) void k_fill(const int* __restrict__ edst,
                                              int* __restrict__ cursor,
                                              int* __restrict__ elist) {
  const int e = blockIdx.x * 256 + threadIdx.x;
  if (e < NE) {
    const int p = atomicAdd(&cursor[edst[e]], 1);
    elist[p] = e;
  }
}

// ---------------- W2^T fp16 hi/lo prep ----------------
template <bool IS2>
__global__ __launch_bounds__(256) void k_prep_w2t(const float* __restrict__ W2,
                                                  ushort* __restrict__ Th,
                                                  ushort* __restrict__ Tl) {
  const int idx = blockIdx.x * 256 + threadIdx.x;
  if (idx >= 128 * 1024) return;
  const int o = idx >> 10, kf = idx & 1023;
  const float v = IS2 ? W2[(size_t)(kf >> 4) * 2176 + (kf & 15) * 128 + o]
                      : W2[(size_t)kf * 128 + o];
  const _Float16 h = (_Float16)v;
  ((_Float16*)Th)[idx] = h;
  ((_Float16*)Tl)[idx] = (_Float16)(v - (float)h);
}

__global__ __launch_bounds__(256) void k_prep_selfw(const float* __restrict__ W2,
                                                    ushort* __restrict__ Sh,
                                                    ushort* __restrict__ Sl) {
  const int idx = blockIdx.x * 256 + threadIdx.x;
  if (idx >= 128 * 64) return;
  const int o = idx >> 6, k = idx & 63;
  const float v = W2[(size_t)k * 2176 + 2048 + o];
  const _Float16 h = (_Float16)v;
  ((_Float16*)Sh)[idx] = h;
  ((_Float16*)Sl)[idx] = (_Float16)(v - (float)h);
}

// ---------------- per-edge bilinear GEMM via split-fp16 MFMA ----------------
// Block: 64 edges (4 m-tiles), 4 waves; wave w owns n-tiles {2w, 2w+1} (N=32).
// Grid NE/64 = 512 blocks. fp16 3-term split: AhBh + AlBh + AhBl (err ~2^-23).
#define MSG_STEP(HS, BH, BL)                                                     \
  do {                                                                           \
    half8 ah_[4], al_[4];                                                        \
    _Pragma("unroll") for (int mt = 0; mt < 4; ++mt) {                           \
      float p_[8];                                                               \
      _Pragma("unroll") for (int j = 0; j < 8; ++j) p_[j] = HS[mt] * nf8[mt][j]; \
      split8h(p_, ah_[mt], al_[mt]);                                             \
    }                                                                            \
    _Pragma("unroll") for (int n = 0; n < 2; ++n) {                              \
      _Pragma("unroll") for (int mt = 0; mt < 4; ++mt) {                         \
        acc[mt][n] = __builtin_amdgcn_mfma_f32_16x16x32_f16(ah_[mt], BH[n], acc[mt][n], 0, 0, 0); \
        acc[mt][n] = __builtin_amdgcn_mfma_f32_16x16x32_f16(al_[mt], BH[n], acc[mt][n], 0, 0, 0); \
        acc[mt][n] = __builtin_amdgcn_mfma_f32_16x16x32_f16(ah_[mt], BL[n], acc[mt][n], 0, 0, 0); \
      }                                                                          \
    }                                                                            \
  } while (0)

template <bool IS2>
__global__ __launch_bounds__(256) void k_msg_mfma(
    const float* __restrict__ u_, const float* __restrict__ cut_,
    const float* __restrict__ W1, const float* __restrict__ bvec,
    const ushort* __restrict__ W2Th, const ushort* __restrict__ W2Tl,
    const ushort* __restrict__ SWh, const ushort* __restrict__ SWl,
    const float* __restrict__ feat16, const int* __restrict__ esrc,
    float* __restrict__ t_, float* __restrict__ self_) {
  __shared__ float hhL[64 * 65];
  __shared__ float nfL[64 * 17];
  __shared__ float uL[64], cL[64];
  __shared__ int sL[64];
  const int tid = threadIdx.x;
  const int e0 = blockIdx.x * 64;
  if (tid < 64) {
    uL[tid] = u_[e0 + tid];
    cL[tid] = cut_[e0 + tid];
    sL[tid] = esrc[e0 + tid];
  }
  __syncthreads();
  for (int i = tid; i < 64 * 64; i += 256) {
    const int e = i >> 6, k = i & 63;
    hhL[e * 65 + k] = fmaxf(fmaf(uL[e], W1[k], bvec[k]), 0.f) * cL[e];
  }
  for (int i = tid; i < 64 * 16; i += 256) {
    const int e = i >> 4, f = i & 15;
    nfL[e * 17 + f] = feat16[(size_t)sL[e] * 16 + f];
  }
  __syncthreads();

  const int lane = tid & 63, wv = tid >> 6;
  const int lr = lane & 15, lg = lane >> 4;
  const int n0 = wv * 2;

  if (IS2) {
    f32x4 sacc[4][2];
#pragma unroll
    for (int mt = 0; mt < 4; ++mt)
#pragma unroll
      for (int n = 0; n < 2; ++n) {
        f32x4 zz = {0.f, 0.f, 0.f, 0.f};
        sacc[mt][n] = zz;
      }
#pragma unroll
    for (int ks2 = 0; ks2 < 2; ++ks2) {
      half8 ash[4], asl[4];
#pragma unroll
      for (int mt = 0; mt < 4; ++mt) {
        float p[8];
        const float* hp = &hhL[(mt * 16 + lr) * 65 + ks2 * 32 + lg * 8];
#pragma unroll
        for (int j = 0; j < 8; ++j) p[j] = hp[j];
        split8h(p, ash[mt], asl[mt]);
      }
#pragma unroll
      for (int n = 0; n < 2; ++n) {
        const half8 bh = *(const half8*)&SWh[((n0 + n) * 16 + lr) * 64 + ks2 * 32 + lg * 8];
        const half8 bl = *(const half8*)&SWl[((n0 + n) * 16 + lr) * 64 + ks2 * 32 + lg * 8];
#pragma unroll
        for (int mt = 0; mt < 4; ++mt) {
          sacc[mt][n] = __builtin_amdgcn_mfma_f32_16x16x32_f16(ash[mt], bh, sacc[mt][n], 0, 0, 0);
          sacc[mt][n] = __builtin_amdgcn_mfma_f32_16x16x32_f16(asl[mt], bh, sacc[mt][n], 0, 0, 0);
          sacc[mt][n] = __builtin_amdgcn_mfma_f32_16x16x32_f16(ash[mt], bl, sacc[mt][n], 0, 0, 0);
        }
      }
    }
#pragma unroll
    for (int mt = 0; mt < 4; ++mt)
#pragma unroll
      for (int n = 0; n < 2; ++n)
#pragma unroll
        for (int i = 0; i < 4; ++i)
          self_[(size_t)(e0 + mt * 16 + lg * 4 + i) * 128 + (n0 + n) * 16 + lr] =
              sacc[mt][n][i] * 0.5f;
  }

  float nf8[4][8];
#pragma unroll
  for (int mt = 0; mt < 4; ++mt)
#pragma unroll
    for (int j = 0; j < 8; ++j)
      nf8[mt][j] = nfL[(mt * 16 + lr) * 17 + (lg & 1) * 8 + j];

  f32x4 acc[4][2];
#pragma unroll
  for (int mt = 0; mt < 4; ++mt)
#pragma unroll
    for (int n = 0; n < 2; ++n) {
      f32x4 zz = {0.f, 0.f, 0.f, 0.f};
      acc[mt][n] = zz;
    }

  const ushort* bh_base[2] = {
    &W2Th[(size_t)((n0 + 0) * 16 + lr) * 1024 + lg * 8],
    &W2Th[(size_t)((n0 + 1) * 16 + lr) * 1024 + lg * 8]};
  const ushort* bl_base[2] = {
    &W2Tl[(size_t)((n0 + 0) * 16 + lr) * 1024 + lg * 8],
    &W2Tl[(size_t)((n0 + 1) * 16 + lr) * 1024 + lg * 8]};
  const float* hs_base[4] = {&hhL[(0 * 16 + lr) * 65 + (lg >> 1)],
                             &hhL[(1 * 16 + lr) * 65 + (lg >> 1)],
                             &hhL[(2 * 16 + lr) * 65 + (lg >> 1)],
                             &hhL[(3 * 16 + lr) * 65 + (lg >> 1)]};

  // static double-buffer: A holds even ks, B holds odd ks
  half8 bhA[2], blA[2], bhB[2], blB[2];
  float hsA[4], hsB[4];
#pragma unroll
  for (int n = 0; n < 2; ++n) {
    bhA[n] = *(const half8*)(bh_base[n]);
    blA[n] = *(const half8*)(bl_base[n]);
  }
#pragma unroll
  for (int mt = 0; mt < 4; ++mt) hsA[mt] = hs_base[mt][0];

  for (int ks = 0; ks < 32; ks += 2) {
#pragma unroll
    for (int n = 0; n < 2; ++n) {
      bhB[n] = *(const half8*)(bh_base[n] + (ks + 1) * 32);
      blB[n] = *(const half8*)(bl_base[n] + (ks + 1) * 32);
    }
#pragma unroll
    for (int mt = 0; mt < 4; ++mt) hsB[mt] = hs_base[mt][2 * (ks + 1)];
    MSG_STEP(hsA, bhA, blA);
    if (ks + 2 < 32) {
#pragma unroll
      for (int n = 0; n < 2; ++n) {
        bhA[n] = *(const half8*)(bh_base[n] + (ks + 2) * 32);
        blA[n] = *(const half8*)(bl_base[n] + (ks + 2) * 32);
      }
#pragma unroll
      for (int mt = 0; mt < 4; ++mt) hsA[mt] = hs_base[mt][2 * (ks + 2)];
    }
    MSG_STEP(hsB, bhB, blB);
  }
#pragma unroll
  for (int mt = 0; mt < 4; ++mt)
#pragma unroll
    for (int n = 0; n < 2; ++n)
#pragma unroll
      for (int i = 0; i < 4; ++i)
        t_[(size_t)(e0 + mt * 16 + lg * 4 + i) * 128 + (n0 + n) * 16 + lr] =
            acc[mt][n][i] * 0.125f;  // 1/sqrt(F)/deg
}

// ---------------- gather (segment sum over incoming edges) + gate ----------------
__global__ __launch_bounds__(256) void k_gather1(
    const float* __restrict__ t_, const float* __restrict__ Y_,
    const int* __restrict__ offs, const int* __restrict__ elist,
    float* __restrict__ h1, float* __restrict__ h1s) {
  __shared__ float tL[128], YL[16], sG[32];
  const int n = blockIdx.x, tid = threadIdx.x;
  const int beg = offs[n], end = offs[n + 1];
  const int cc = tid & 15;
  const int lx = lidx_of(cc);
  const int o0 = ((tid >> 4) << 2) + lx;
  const int o1 = o0 + 64;
  float a0 = 0.f, a1 = 0.f;
  for (int ei = beg; ei < end; ++ei) {
    const int e = elist[ei];
    __syncthreads();
    if (tid < 128) tL[tid] = t_[(size_t)e * 128 + tid];
    else if (tid < 144) YL[tid - 128] = Y_[(size_t)e * 16 + tid - 128];
    __syncthreads();
    const float yv = YL[cc];
    a0 = fmaf(tL[o0], yv, a0);
    a1 = fmaf(tL[o1], yv, a1);
  }
  if (cc == 0) { sG[tid >> 4] = a0; sG[(tid >> 4) + 16] = a1; }
  __syncthreads();
  const float s0 = sG[tid >> 4], s1 = sG[(tid >> 4) + 16];
  const float r0 = (cc == 0) ? fmaxf(a0, 0.f) : a0 * (1.f / (1.f + expf(-s0)));
  const float r1 = (cc == 0) ? fmaxf(a1, 0.f) : a1 * (1.f / (1.f + expf(-s1)));
  h1[(size_t)n * 512 + tid] = r0;
  h1[(size_t)n * 512 + tid + 256] = r1;
  if ((tid & 31) == 0) {
    h1s[n * 16 + (tid >> 5)] = r0;
    h1s[n * 16 + (tid >> 5) + 8] = r1;
  }
}

__global__ __launch_bounds__(256) void k_gather2(
    const float* __restrict__ t_, const float* __restrict__ self_,
    const float* __restrict__ Y_, const float* __restrict__ h1,
    const int* __restrict__ offs, const int* __restrict__ elist,
    const int* __restrict__ esrc, float* __restrict__ h2) {
  __shared__ float tL[128], wL[128], YL[16], sG[32];
  const int n = blockIdx.x, tid = threadIdx.x;
  const int beg = offs[n], end = offs[n + 1];
  const int cc = tid & 15;
  const int lx = lidx_of(cc);
  const int o0 = ((tid >> 4) << 2) + lx;
  const int o1 = o0 + 64;
  float a0 = 0.f, a1 = 0.f;
  for (int ei = beg; ei < end; ++ei) {
    const int e = elist[ei];
    __syncthreads();
    if (tid < 128) tL[tid] = t_[(size_t)e * 128 + tid];
    else wL[tid - 128] = self_[(size_t)e * 128 + tid - 128];
    if (tid < 16) YL[tid] = Y_[(size_t)e * 16 + tid];
    __syncthreads();
    const int src = esrc[e];
    const float* hr = &h1[(size_t)src * 512];
    const float yv = YL[cc];
    a0 += tL[o0] * yv + hr[tid] * wL[o0];
    a1 += tL[o1] * yv + hr[tid + 256] * wL[o1];
  }
  if (cc == 0) { sG[tid >> 4] = a0; sG[(tid >> 4) + 16] = a1; }
  __syncthreads();
  const float s0 = sG[tid >> 4], s1 = sG[(tid >> 4) + 16];
  const float r0 = (cc == 0) ? fmaxf(a0, 0.f) : a0 * (1.f / (1.f + expf(-s0)));
  const float r1 = (cc == 0) ? fmaxf(a1, 0.f) : a1 * (1.f / (1.f + expf(-s1)));
  h2[(size_t)n * 512 + tid] = r0;
  h2[(size_t)n * 512 + tid + 256] = r1;
}

// ---------------- mean pool over each graph's 256 nodes ----------------
__global__ __launch_bounds__(256) void k_pool(const float* __restrict__ h2,
                                              float* __restrict__ enc) {
  const int b = blockIdx.x, tid = threadIdx.x;
  float a0 = 0.f, a1 = 0.f;
  for (int i = 0; i < 256; ++i) {
    const float* row = &h2[(size_t)(b * 256 + i) * 512];
    a0 += row[tid];
    a1 += row[tid + 256];
  }
  enc[b * 512 + tid] = a0 * (1.f / 256.f);
  enc[b * 512 + tid + 256] = a1 * (1.f / 256.f);
}

// ---------------- z = per-l linear mix of enc (B,32,16) -> (B,16,84) ----------------
__global__ __launch_bounds__(256) void k_zproj(const float* __restrict__ enc,
                                               const float* __restrict__ Wlin,
                                               float* __restrict__ z) {
  __shared__ float eL[512];
  const int b = blockIdx.x, tid = threadIdx.x;
  eL[tid] = enc[b * 512 + tid];
  eL[tid + 256] = enc[b * 512 + tid + 256];
  __syncthreads();
  for (int idx = tid; idx < 16 * 84; idx += 256) {
    const int g = idx / 84, d3 = idx % 84;
    int o0, m0, mo;
    if (d3 < 1)       { o0 = 0;  m0 = 1; mo = 0; }
    else if (d3 < 10) { o0 = 1;  m0 = 3; mo = 1; }
    else if (d3 < 35) { o0 = 10; m0 = 5; mo = 4; }
    else              { o0 = 35; m0 = 7; mo = 9; }
    const int rem = d3 - o0;
    const int jj = rem / m0;
    const int cc2 = rem - jj * m0;
    float a = 0.f;
    for (int mu = 0; mu < 32; ++mu)
      a = fmaf(eL[mu * 16 + mo + cc2], Wlin[(mu * 16 + g) * 16 + mo + jj], a);
    z[(size_t)(b * 16 + g) * 84 + d3] = a * 0.17677669529663687f;  // 1/sqrt(32)
  }
}

// ---------------- SO3 conv as split-bf16 MFMA GEMMs ----------------
template <int FI>
__global__ __launch_bounds__(256) void k_prep_xg(const float* __restrict__ x,
                                                 ushort* __restrict__ Xh,
                                                 ushort* __restrict__ Xl) {
  constexpr int KP0 = (FI + 31) & ~31, KP1 = (3 * FI + 31) & ~31;
  constexpr int KP2 = (5 * FI + 31) & ~31, KP3 = (7 * FI + 31) & ~31;
  constexpr int XO1 = 32 * KP0, XO2 = XO1 + 96 * KP1, XO3 = XO2 + 160 * KP2;
  constexpr int TOT = XO3 + 224 * KP3;
  const int idx = blockIdx.x * 256 + threadIdx.x;
  if (idx >= TOT) return;
  int m, o0, base, KP;
  if (idx < XO1)      { m = 1; o0 = 0;  base = 0;   KP = KP0; }
  else if (idx < XO2) { m = 3; o0 = 1;  base = XO1; KP = KP1; }
  else if (idx < XO3) { m = 5; o0 = 10; base = XO2; KP = KP2; }
  else                { m = 7; o0 = 35; base = XO3; KP = KP3; }
  const int rel = idx - base;
  const int r = rel / KP, k = rel % KP;
  ushort h = 0, lo = 0;
  if (k < FI * m) {
    const int f = k / m, i = k % m, b = r / m, c = r % m;
    const float v = x[((size_t)b * FI + f) * 84 + o0 + i * m + c];
    h = f2bf(v);
    lo = (ushort)(__float_as_uint(v - bf2f(h)) >> 16);
  }
  Xh[idx] = h;
  Xl[idx] = lo;
}

template <int FI, int FO>
__global__ __launch_bounds__(256) void k_prep_psig(const float* __restrict__ psi,
                                                   ushort* __restrict__ Ph,
                                                   ushort* __restrict__ Pl) {
  constexpr int KP0 = (FI + 31) & ~31, KP1 = (3 * FI + 31) & ~31;
  constexpr int KP2 = (5 * FI + 31) & ~31, KP3 = (7 * FI + 31) & ~31;
  constexpr int PO1 = FO * KP0, PO2 = PO1 + 3 * FO * KP1, PO3 = PO2 + 5 * FO * KP2;
  constexpr int TOT = PO3 + 7 * FO * KP3;
  const int idx = blockIdx.x * 256 + threadIdx.x;
  if (idx >= TOT) return;
  int m, o0, base, KP;
  if (idx < PO1)      { m = 1; o0 = 0;  base = 0;   KP = KP0; }
  else if (idx < PO2) { m = 3; o0 = 1;  base = PO1; KP = KP1; }
  else if (idx < PO3) { m = 5; o0 = 10; base = PO2; KP = KP2; }
  else                { m = 7; o0 = 35; base = PO3; KP = KP3; }
  const int rel = idx - base;
  const int n = rel / KP, k = rel % KP;
  ushort h = 0, lo = 0;
  if (k < FI * m) {
    const int f = k / m, i = k % m, g = n / m, j = n % m;
    const float v = psi[((size_t)f * FO + g) * 84 + o0 + i * m + j];
    h = f2bf(v);
    lo = (ushort)(__float_as_uint(v - bf2f(h)) >> 16);
  }
  Ph[idx] = h;
  Pl[idx] = lo;
}

template <int FI, int FO>
__global__ __launch_bounds__(256) void k_conv_gemm(
    const ushort* __restrict__ Xh, const ushort* __restrict__ Xl,
    const ushort* __restrict__ Ph, const ushort* __restrict__ Pl,
    float* __restrict__ out) {
  constexpr int KP0 = (FI + 31) & ~31, KP1 = (3 * FI + 31) & ~31;
  constexpr int KP2 = (5 * FI + 31) & ~31, KP3 = (7 * FI + 31) & ~31;
  constexpr int XO1 = 32 * KP0, XO2 = XO1 + 96 * KP1, XO3 = XO2 + 160 * KP2;
  constexpr int PO1 = FO * KP0, PO2 = PO1 + 3 * FO * KP1, PO3 = PO2 + 5 * FO * KP2;
  constexpr int NT0 = 1 * (FO / 32), NT1 = 3 * (3 * FO / 32);
  constexpr int NT2 = 5 * (5 * FO / 32), NT3 = 7 * (7 * FO / 32);
  constexpr int TB1 = NT0, TB2 = TB1 + NT1, TB3 = TB2 + NT2, TOT = TB3 + NT3;

  const int wt = blockIdx.x * 4 + (threadIdx.x >> 6);
  if (wt >= TOT) return;
  int m, o0, Mt, KP, Xo, Po, loc;
  if (wt < TB1)      { m = 1; o0 = 0;  Mt = 1; KP = KP0; Xo = 0;   Po = 0;   loc = wt; }
  else if (wt < TB2) { m = 3; o0 = 1;  Mt = 3; KP = KP1; Xo = XO1; Po = PO1; loc = wt - TB1; }
  else if (wt < TB3) { m = 5; o0 = 10; Mt = 5; KP = KP2; Xo = XO2; Po = PO2; loc = wt - TB2; }
  else               { m = 7; o0 = 35; Mt = 7; KP = KP3; Xo = XO3; Po = PO3; loc = wt - TB3; }
  const int mt0 = (loc % Mt) * 32;
  const int nt0 = (loc / Mt) * 32;
  const int lane = threadIdx.x & 63, lr = lane & 15, lg = lane >> 4;

  f32x4 acc[2][2];
#pragma unroll
  for (int mt = 0; mt < 2; ++mt)
#pragma unroll
    for (int nt = 0; nt < 2; ++nt) {
      f32x4 zz = {0.f, 0.f, 0.f, 0.f};
      acc[mt][nt] = zz;
    }

  const int nks = KP >> 5;
  for (int ks = 0; ks < nks; ++ks) {
    short8 ah[2], al[2], bh[2], bl[2];
#pragma unroll
    for (int t = 0; t < 2; ++t) {
      const size_t xa = (size_t)Xo + (size_t)(mt0 + t * 16 + lr) * KP + ks * 32 + lg * 8;
      ah[t] = *(const short8*)&Xh[xa];
      al[t] = *(const short8*)&Xl[xa];
      const size_t pa = (size_t)Po + (size_t)(nt0 + t * 16 + lr) * KP + ks * 32 + lg * 8;
      bh[t] = *(const short8*)&Ph[pa];
      bl[t] = *(const short8*)&Pl[pa];
    }
#pragma unroll
    for (int nt = 0; nt < 2; ++nt)
#pragma unroll
      for (int mt = 0; mt < 2; ++mt) {
        acc[mt][nt] = __builtin_amdgcn_mfma_f32_16x16x32_bf16(ah[mt], bh[nt], acc[mt][nt], 0, 0, 0);
        acc[mt][nt] = __builtin_amdgcn_mfma_f32_16x16x32_bf16(al[mt], bh[nt], acc[mt][nt], 0, 0, 0);
        acc[mt][nt] = __builtin_amdgcn_mfma_f32_16x16x32_bf16(ah[mt], bl[nt], acc[mt][nt], 0, 0, 0);
      }
  }

  const float scale = 1.f / sqrtf((float)(FI * m));
#pragma unroll
  for (int mt = 0; mt < 2; ++mt)
#pragma unroll
    for (int nt = 0; nt < 2; ++nt)
#pragma unroll
      for (int i = 0; i < 4; ++i) {
        const int R = mt0 + mt * 16 + lg * 4 + i;
        const int C2 = nt0 + nt * 16 + lr;
        const int b = R / m, c = R - b * m;
        const int g = C2 / m, j = C2 - g * m;
        out[((size_t)b * FO + g) * 84 + o0 + j * m + c] = acc[mt][nt][i] * scale;
      }
}

// ---------------- weight prep for MFMA act ----------------
__global__ __launch_bounds__(256) void k_prep_gt(const float* __restrict__ Gt,
                                                 ushort* __restrict__ GtT) {
  const int idx = blockIdx.x * 256 + threadIdx.x;
  if (idx >= 4096 * 96) return;
  const int g = idx / 96, k = idx % 96;
  GtT[idx] = (k < 84) ? f2bf(Gt[(size_t)k * 4096 + g]) : (ushort)0;
}
__global__ __launch_bounds__(256) void k_prep_gf(const float* __restrict__ Gf,
                                                 ushort* __restrict__ GfT) {
  const int idx = blockIdx.x * 256 + threadIdx.x;
  if (idx >= 96 * 4096) return;
  const int d = idx / 4096, g = idx % 4096;
  GfT[idx] = (d < 84) ? f2bf(Gf[(size_t)g * 84 + d]) : (ushort)0;
}
__global__ __launch_bounds__(256) void k_cvtx(const float* __restrict__ x,
                                              ushort* __restrict__ Xb, int total) {
  const int idx = blockIdx.x * 256 + threadIdx.x;
  if (idx >= total) return;
  const int r = idx / 96, k = idx % 96;
  Xb[idx] = (k < 84) ? f2bf(x[(size_t)r * 84 + k]) : (ushort)0;
}

// ---------------- SO3 act via bf16 MFMA (fused, g-split partials) ----------------
template <int GS>
__global__ __launch_bounds__(256) void k_act_mfma(
    const ushort* __restrict__ Xb, const ushort* __restrict__ GtT,
    const ushort* __restrict__ GfT, float* __restrict__ part, int NR) {
  constexpr int CPB = 64 / GS;
  __shared__ __align__(16) ushort ldsGt[64 * 104];
  __shared__ __align__(16) ushort ldsH[128 * 72];
  __shared__ __align__(16) ushort ldsGf[96 * 72];
  const int tid = threadIdx.x;
  const int gs = blockIdx.x;
  const int row0 = blockIdx.y * 128;
  const int lane = tid & 63, wv = tid >> 6;
  const int lr = lane & 15, lg = lane >> 4;
  const int m0 = wv * 32;

  short8 a1[2][3];
#pragma unroll
  for (int mt = 0; mt < 2; ++mt)
#pragma unroll
    for (int ks = 0; ks < 3; ++ks)
      a1[mt][ks] = *(const short8*)&Xb[(size_t)(row0 + m0 + mt * 16 + lr) * 96 +
                                       ks * 32 + lg * 8];

  f32x4 acc2[6][2];
#pragma unroll
  for (int m2 = 0; m2 < 6; ++m2)
#pragma unroll
    for (int n2 = 0; n2 < 2; ++n2) {
      f32x4 zz = {0.f, 0.f, 0.f, 0.f};
      acc2[m2][n2] = zz;
    }

  for (int ch = gs * CPB; ch < (gs + 1) * CPB; ++ch) {
    const int g0 = ch * 64;
    __syncthreads();
    for (int i = tid; i < 768; i += 256) {
      const int row = i / 12, c = i % 12;
      *(uint4*)&ldsGt[row * 104 + c * 8] =
          *(const uint4*)&GtT[(size_t)(g0 + row) * 96 + c * 8];
    }
    for (int i = tid; i < 768; i += 256) {
      const int row = i / 8, c = i % 8;
      *(uint4*)&ldsGf[row * 72 + c * 8] =
          *(const uint4*)&GfT[(size_t)row * 4096 + g0 + c * 8];
    }
    __syncthreads();
#pragma unroll
    for (int n = 0; n < 4; ++n) {
      short8 b[3];
#pragma unroll
      for (int ks = 0; ks < 3; ++ks)
        b[ks] = *(const short8*)&ldsGt[(n * 16 + lr) * 104 + ks * 32 + lg * 8];
#pragma unroll
      for (int mt = 0; mt < 2; ++mt) {
        f32x4 c1 = {0.f, 0.f, 0.f, 0.f};
#pragma unroll
        for (int ks = 0; ks < 3; ++ks)
          c1 = __builtin_amdgcn_mfma_f32_16x16x32_bf16(a1[mt][ks], b[ks], c1, 0, 0, 0);
        ushort* hp = &ldsH[(m0 + mt * 16 + lg * 4) * 72 + n * 16 + lr];
#pragma unroll
        for (int i = 0; i < 4; ++i) hp[i * 72] = f2bf(fmaxf(c1[i], 0.f));
      }
    }
#pragma unroll
    for (int k2 = 0; k2 < 2; ++k2) {
      short8 bh[2];
#pragma unroll
      for (int n2 = 0; n2 < 2; ++n2)
        bh[n2] = *(const short8*)&ldsH[(m0 + n2 * 16 + lr) * 72 + k2 * 32 + lg * 8];
#pragma unroll
      for (int m2 = 0; m2 < 6; ++m2) {
        const short8 a2 = *(const short8*)&ldsGf[(m2 * 16 + lr) * 72 + k2 * 32 + lg * 8];
        acc2[m2][0] = __builtin_amdgcn_mfma_f32_16x16x32_bf16(a2, bh[0], acc2[m2][0], 0, 0, 0);
        acc2[m2][1] = __builtin_amdgcn_mfma_f32_16x16x32_bf16(a2, bh[1], acc2[m2][1], 0, 0, 0);
      }
    }
  }
#pragma unroll
  for (int m2 = 0; m2 < 6; ++m2)
#pragma unroll
    for (int n2 = 0; n2 < 2; ++n2)
#pragma unroll
      for (int i = 0; i < 4; ++i) {
        const int d = m2 * 16 + lg * 4 + i;
        if (d < 84) {
          const int r = row0 + m0 + n2 * 16 + lr;
          part[((size_t)gs * NR + r) * 84 + d] = acc2[m2][n2][i];
        }
      }
}

template <int GS>
__global__ __launch_bounds__(256) void k_act_reduce(const float* __restrict__ part,
                                                    float* __restrict__ out, int total) {
  const int i = blockIdx.x * 256 + threadIdx.x;
  if (i < total) {
    float s = part[i];
#pragma unroll
    for (int g = 1; g < GS; ++g) s += part[(size_t)g * total + i];
    out[i] = s * (1.f / (9.16515138991168f * 64.f));
  }
}

// ---------------- final: Ws2 contraction + orientation SH dot ----------------
__global__ __launch_bounds__(256) void k_final(const float* __restrict__ x,
                                               const float* __restrict__ Ws2,
                                               const float* __restrict__ orient,
                                               float* __restrict__ outp) {
  __shared__ float red[256][16];
  const int b = blockIdx.x, tid = threadIdx.x;
  const float* xr = &x[(size_t)(b * 256 + tid) * 84];
  const float* wr = &Ws2[tid * 16];
  float acc[16];
#pragma unroll
  for (int c = 0; c < 16; ++c) acc[c] = 0.f;
  acc[0] = fmaf(xr[0], wr[0], acc[0]);
#pragma unroll
  for (int i = 0; i < 3; ++i) {
    const float w = wr[1 + i];
#pragma unroll
    for (int c = 0; c < 3; ++c) acc[1 + c] = fmaf(xr[1 + i * 3 + c], w, acc[1 + c]);
  }
#pragma unroll
  for (int i = 0; i < 5; ++i) {
    const float w = wr[4 + i];
#pragma unroll
    for (int c = 0; c < 5; ++c) acc[4 + c] = fmaf(xr[10 + i * 5 + c], w, acc[4 + c]);
  }
#pragma unroll
  for (int i = 0; i < 7; ++i) {
    const float w = wr[9 + i];
#pragma unroll
    for (int c = 0; c < 7; ++c) acc[9 + c] = fmaf(xr[35 + i * 7 + c], w, acc[9 + c]);
  }
#pragma unroll
  for (int c = 0; c < 16; ++c) red[tid][c] = acc[c];
  __syncthreads();
  for (int off = 128; off > 0; off >>= 1) {
    if (tid < off)
#pragma unroll
      for (int c = 0; c < 16; ++c) red[tid][c] += red[tid + off][c];
    __syncthreads();
  }
  if (tid == 0) {
    const float aa = orient[b * 2 + 0], rr = orient[b * 2 + 1];
    float Y[16];
    real_sh_f(-sinf(aa) * cosf(rr), -sinf(aa) * sinf(rr), -cosf(aa), Y);
    const float sc1 = 1.f / 16.f;
    const float sc3 = 1.f / (16.f * 1.7320508075688772f);
    const float sc5 = 1.f / (16.f * 2.23606797749979f);
    const float sc7 = 1.f / (16.f * 2.6457513110645907f);
    float o = red[0][0] * sc1 * Y[0];
#pragma unroll
    for (int c = 1; c < 4; ++c) o += red[0][c] * sc3 * Y[c];
#pragma unroll
    for (int c = 4; c < 9; ++c) o += red[0][c] * sc5 * Y[c];
#pragma unroll
    for (int c = 9; c < 16; ++c) o += red[0][c] * sc7 * Y[c];
    outp[b] = o;
  }
}

extern "C" void kernel_launch(void* const* d_in, const int* in_sizes, int n_in,
                              void* d_out, int out_size, void* d_ws, size_t ws_size,
                              hipStream_t stream) {
  const float* node_feat = (const float*)d_in[0];
  const float* pos       = (const float*)d_in[1];
  const float* orient    = (const float*)d_in[2];
  const float* rad1_W1   = (const float*)d_in[3];
  const float* rad1_b    = (const float*)d_in[4];
  const float* rad1_W2   = (const float*)d_in[5];
  const float* rad2_W1   = (const float*)d_in[6];
  const float* rad2_b    = (const float*)d_in[7];
  const float* rad2_W2   = (const float*)d_in[8];
  const float* Wlin      = (const float*)d_in[9];
  const float* psi1      = (const float*)d_in[10];
  const float* psi2      = (const float*)d_in[11];
  const float* psi3      = (const float*)d_in[12];
  const float* G_to      = (const float*)d_in[13];
  const float* G_from    = (const float*)d_in[14];
  const float* Ws2       = (const float*)d_in[15];
  const int*   esrc      = (const int*)d_in[16];
  const int*   edst      = (const int*)d_in[17];

  float* w = (float*)d_ws;
  size_t off = 0;
  float* u_    = w + off; off += NE;
  float* cut_  = w + off; off += NE;
  float* Y_    = w + off; off += (size_t)NE * 16;   // later: Xp hi/lo (bf16)
  float* t_    = w + off; off += (size_t)NE * 128;  // t1/t2; later act partials
  float* self_ = w + off; off += (size_t)NE * 128;
  float* h1    = w + off; off += (size_t)NN * 512;  // later: GtT/GfT/Xb (bf16)
  float* h1s   = w + off; off += (size_t)NN * 16;
  float* h2    = w + off; off += (size_t)NN * 512;  // later: Psi-p hi/lo (bf16)
  float* enc   = w + off; off += (size_t)NB * 512;
  float* z     = w + off; off += (size_t)NB * 16 * 84;
  float* xb1   = w + off; off += (size_t)NB * 256 * 84;
  float* xb2   = w + off; off += (size_t)NB * 256 * 84;
  int* cnt    = (int*)(w + off); off += NN;
  int* offs   = (int*)(w + off); off += NN + 1;
  int* cursor = (int*)(w + off); off += NN;
  int* elist  = (int*)(w + off); off += NE;
  ushort* W2Th = (ushort*)(w + off); off += 65536;
  ushort* W2Tl = (ushort*)(w + off); off += 65536;
  ushort* SWh  = (ushort*)(w + off); off += 4096;
  ushort* SWl  = (ushort*)(w + off); off += 4096;

  // reuse of dead buffers during conv/act chain:
  float* part = t_;
  ushort* GtT = (ushort*)h1;
  ushort* GfT = GtT + 4096 * 96;
  ushort* Xb  = GfT + 96 * 4096;
  ushort* Xph = (ushort*)Y_;
  ushort* Xpl = Xph + 344064;
  ushort* Pph = (ushort*)h2;
  ushort* Ppl = Pph + 2752512;

  hipMemsetAsync(cnt, 0, NN * sizeof(int), stream);
  k_edge_prep<<<NE / 256, 256, 0, stream>>>(pos, esrc, edst, u_, cut_, Y_, cnt);
  k_scan<<<1, 256, 0, stream>>>(cnt, offs, cursor);
  k_fill<<<NE / 256, 256, 0, stream>>>(edst, cursor, elist);

  k_prep_w2t<false><<<512, 256, 0, stream>>>(rad1_W2, W2Th, W2Tl);
  k_msg_mfma<false><<<NE / 64, 256, 0, stream>>>(u_, cut_, rad1_W1, rad1_b, W2Th, W2Tl,
                                                 nullptr, nullptr, node_feat, esrc,
                                                 t_, nullptr);
  k_gather1<<<NN, 256, 0, stream>>>(t_, Y_, offs, elist, h1, h1s);

  k_prep_w2t<true><<<512, 256, 0, stream>>>(rad2_W2, W2Th, W2Tl);
  k_prep_selfw<<<32, 256, 0, stream>>>(rad2_W2, SWh, SWl);
  k_msg_mfma<true><<<NE / 64, 256, 0, stream>>>(u_, cut_, rad2_W1, rad2_b, W2Th, W2Tl,
                                                SWh, SWl, h1s, esrc, t_, self_);
  k_gather2<<<NN, 256, 0, stream>>>(t_, self_, Y_, h1, offs, elist, esrc, h2);
  k_pool<<<NB, 256, 0, stream>>>(h2, enc);
  k_zproj<<<NB, 256, 0, stream>>>(enc, Wlin, z);

  k_prep_gt<<<(4096 * 96 + 255) / 256, 256, 0, stream>>>(G_to, GtT);
  k_prep_gf<<<(96 * 4096 + 255) / 256, 256, 0, stream>>>(G_from, GfT);

  // ---- stage 1
  k_prep_psig<16, 64><<<(102400 + 255) / 256, 256, 0, stream>>>(psi1, Pph, Ppl);
  k_prep_xg<16><<<(51200 + 255) / 256, 256, 0, stream>>>(z, Xph, Xpl);
  k_conv_gemm<16, 64><<<42, 256, 0, stream>>>(Xph, Xpl, Pph, Ppl, xb1);
  k_cvtx<<<(2048 * 96 + 255) / 256, 256, 0, stream>>>(xb1, Xb, 2048 * 96);
  k_act_mfma<32><<<dim3(32, 16), 256, 0, stream>>>(Xb, GtT, GfT, part, 2048);
  k_act_reduce<32><<<(2048 * 84 + 255) / 256, 256, 0, stream>>>(part, xb2, 2048 * 84);

  // ---- stage 2
  k_prep_psig<64, 128><<<(688128 + 255) / 256, 256, 0, stream>>>(psi2, Pph, Ppl);
  k_prep_xg<64><<<(172032 + 255) / 256, 256, 0, stream>>>(xb2, Xph, Xpl);
  k_conv_gemm<64, 128><<<84, 256, 0, stream>>>(Xph, Xpl, Pph, Ppl, xb1);
  k_cvtx<<<(4096 * 96 + 255) / 256, 256, 0, stream>>>(xb1, Xb, 4096 * 96);
  k_act_mfma<16><<<dim3(16, 32), 256, 0, stream>>>(Xb, GtT, GfT, part, 4096);
  k_act_reduce<16><<<(4096 * 84 + 255) / 256, 256, 0, stream>>>(part, xb2, 4096 * 84);

  // ---- stage 3
  k_prep_psig<128, 256><<<(2752512 + 255) / 256, 256, 0, stream>>>(psi3, Pph, Ppl);
  k_prep_xg<128><<<(344064 + 255) / 256, 256, 0, stream>>>(xb2, Xph, Xpl);
  k_conv_gemm<128, 256><<<168, 256, 0, stream>>>(Xph, Xpl, Pph, Ppl, xb1);
  k_cvtx<<<(8192 * 96 + 255) / 256, 256, 0, stream>>>(xb1, Xb, 8192 * 96);
  k_act_mfma<8><<<dim3(8, 64), 256, 0, stream>>>(Xb, GtT, GfT, part, 8192);
  k_act_reduce<8><<<(8192 * 84 + 255) / 256, 256, 0, stream>>>(part, xb2, 8192 * 84);

  k_final<<<NB, 256, 0, stream>>>(xb2, Ws2, orient, (float*)d_out);
}

// Round 13
// 371.822 us; speedup vs baseline: 4.1101x; 1.0305x over previous
//
#include <hip/hip_runtime.h>
#include <math.h>

#define DEV static __device__ __forceinline__

constexpr int NN = 8192;    // nodes
constexpr int NE = 32768;   // edges
constexpr int NB = 32;      // graphs

using short8 = __attribute__((ext_vector_type(8))) short;
using half8  = __attribute__((ext_vector_type(8))) _Float16;
using f32x4  = __attribute__((ext_vector_type(4))) float;

DEV ushort f2bf(float f) {  // round-to-nearest-even f32 -> bf16 bits
  unsigned u = __float_as_uint(f);
  unsigned r = (u + 0x7FFFu + ((u >> 16) & 1u)) >> 16;
  return (ushort)r;
}
DEV float bf2f(ushort h) { return __uint_as_float(((unsigned)h) << 16); }

// split p[8] into fp16 hi + fp16 residual
DEV void split8h(const float* p, half8& hi, half8& lo) {
#pragma unroll
  for (int j = 0; j < 8; ++j) {
    const _Float16 h = (_Float16)p[j];
    hi[j] = h;
    lo[j] = (_Float16)(p[j] - (float)h);
  }
}

DEV int lidx_of(int c) { return (c == 0) ? 0 : (c < 4) ? 1 : (c < 9) ? 2 : 3; }

DEV void real_sh_f(float x, float y, float z, float* Y) {
  const float s3  = 1.7320508075688772f;
  const float s5  = 2.23606797749979f;
  const float s15 = 3.872983346207417f;
  Y[0] = 1.f;
  Y[1] = s3 * y;  Y[2] = s3 * z;  Y[3] = s3 * x;
  Y[4] = s15 * x * y;
  Y[5] = s15 * y * z;
  Y[6] = 0.5f * s5 * (3.f * z * z - 1.f);
  Y[7] = s15 * x * z;
  Y[8] = 0.5f * s15 * (x * x - y * y);
  Y[9]  = 2.091650066335189f * y * (3.f * x * x - y * y);
  Y[10] = 10.246950765959598f * x * y * z;
  Y[11] = 1.6201851746019651f * y * (5.f * z * z - 1.f);
  Y[12] = 1.3228756555322954f * (5.f * z * z * z - 3.f * z);
  Y[13] = 1.6201851746019651f * x * (5.f * z * z - 1.f);
  Y[14] = 5.123475382979799f * (x * x - y * y) * z;
  Y[15] = 2.091650066335189f * x * (x * x - 3.f * y * y);
}

// ---------------- edge geometry: Y, u, cut + degree histogram ----------------
__global__ __launch_bounds__(256) void k_edge_prep(
    const float* __restrict__ pos, const int* __restrict__ esrc,
    const int* __restrict__ edst, float* __restrict__ u_, float* __restrict__ cut_,
    float* __restrict__ Y_, int* __restrict__ cnt) {
  const int e = blockIdx.x * 256 + threadIdx.x;
  if (e >= NE) return;
  const int s = esrc[e], t = edst[e];
  const float ex = pos[t * 3 + 0] - pos[s * 3 + 0];
  const float ey = pos[t * 3 + 1] - pos[s * 3 + 1];
  const float ez = pos[t * 3 + 2] - pos[s * 3 + 2];
  const float d = sqrtf(ex * ex + ey * ey + ez * ez) + 1e-9f;
  const float inv = 1.f / d;
  float Y[16];
  real_sh_f(ex * inv, ey * inv, ez * inv, Y);
#pragma unroll
  for (int c = 0; c < 16; ++c) Y_[(size_t)e * 16 + c] = Y[c];
  const float u = d / 3.5f;
  u_[e] = u;
  cut_[e] = (u < 1.f) ? 0.5f * (cosf(3.14159265358979323846f * u) + 1.f) : 0.f;
  atomicAdd(&cnt[t], 1);
}

// ---------------- CSR build: scan + fill ----------------
__global__ __launch_bounds__(256) void k_scan(const int* __restrict__ cnt,
                                              int* __restrict__ offs,
                                              int* __restrict__ cursor) {
  __shared__ int part[256];
  const int t = threadIdx.x;
  int s = 0;
  for (int i = 0; i < 32; ++i) s += cnt[t * 32 + i];
  part[t] = s;
  __syncthreads();
  if (t == 0) {
    int run = 0;
    for (int i = 0; i < 256; ++i) { int v = part[i]; part[i] = run; run += v; }
    offs[NN] = run;
  }
  __syncthreads();
  int run = part[t];
  for (int i = 0; i < 32; ++i) {
    const int idx = t * 32 + i;
    offs[idx] = run;
    cursor[idx] = run;
    run += cnt[idx];
  }
}

__global__ __launch_bounds__(256) void k_fill(const int* __restrict__ edst,
                                              int* __restrict__ cursor,
                                              int* __restrict__ elist) {
  const int e = blockIdx.x * 256 + threadIdx.x;
  if (e < NE) {
    const int p = atomicAdd(&cursor[edst[e]], 1);
    elist[p] = e;
  }
}

// ---------------- W2^T fp16 hi/lo prep ----------------
template <bool IS2>
__global__ __launch_bounds__(256) void k_prep_w2t(const float* __restrict__ W2,
                                                  ushort* __restrict__ Th,
                                                  ushort* __restrict__ Tl) {
  const int idx = blockIdx.x * 256 + threadIdx.x;
  if (idx >= 128 * 1024) return;
  const int o = idx >> 10, kf = idx & 1023;
  const float v = IS2 ? W2[(size_t)(kf >> 4) * 2176 + (kf & 15) * 128 + o]
                      : W2[(size_t)kf * 128 + o];
  const _Float16 h = (_Float16)v;
  ((_Float16*)Th)[idx] = h;
  ((_Float16*)Tl)[idx] = (_Float16)(v - (float)h);
}

__global__ __launch_bounds__(256) void k_prep_selfw(const float* __restrict__ W2,
                                                    ushort* __restrict__ Sh,
                                                    ushort* __restrict__ Sl) {
  const int idx = blockIdx.x * 256 + threadIdx.x;
  if (idx >= 128 * 64) return;
  const int o = idx >> 6, k = idx & 63;
  const float v = W2[(size_t)k * 2176 + 2048 + o];
  const _Float16 h = (_Float16)v;
  ((_Float16*)Sh)[idx] = h;
  ((_Float16*)Sl)[idx] = (_Float16)(v - (float)h);
}

// ---------------- per-edge bilinear GEMM via split-fp16 MFMA ----------------
// Block: 64 edges, 512 threads / 8 waves. Wave quad wq = wv&3 owns n-tiles
// {2wq, 2wq+1}; K-half kh = wv>>2 owns ks in [kh*16, kh*16+16). Final combine
// through padded LDS (once per block). Grid NE/64 = 512 -> 16 waves/CU.
#define MSG_STEP(HS, BH, BL)                                                     \
  do {                                                                           \
    half8 ah_[4], al_[4];                                                        \
    _Pragma("unroll") for (int mt = 0; mt < 4; ++mt) {                           \
      float p_[8];                                                               \
      _Pragma("unroll") for (int j = 0; j < 8; ++j) p_[j] = HS[mt] * nf8[mt][j]; \
      split8h(p_, ah_[mt], al_[mt]);                                             \
    }                                                                            \
    _Pragma("unroll") for (int n = 0; n < 2; ++n) {                              \
      _Pragma("unroll") for (int mt = 0; mt < 4; ++mt) {                         \
        acc[mt][n] = __builtin_amdgcn_mfma_f32_16x16x32_f16(ah_[mt], BH[n], acc[mt][n], 0, 0, 0); \
        acc[mt][n] = __builtin_amdgcn_mfma_f32_16x16x32_f16(al_[mt], BH[n], acc[mt][n], 0, 0, 0); \
        acc[mt][n] = __builtin_amdgcn_mfma_f32_16x16x32_f16(ah_[mt], BL[n], acc[mt][n], 0, 0, 0); \
      }                                                                          \
    }                                                                            \
  } while (0)

template <bool IS2>
__global__ __launch_bounds__(512) void k_msg_mfma(
    const float* __restrict__ u_, const float* __restrict__ cut_,
    const float* __restrict__ W1, const float* __restrict__ bvec,
    const ushort* __restrict__ W2Th, const ushort* __restrict__ W2Tl,
    const ushort* __restrict__ SWh, const ushort* __restrict__ SWl,
    const float* __restrict__ feat16, const int* __restrict__ esrc,
    float* __restrict__ t_, float* __restrict__ self_) {
  __shared__ float smem[8448];  // staging (5440) then reduce (4*2112=8448)
  float* uL  = smem;            // 64
  float* cL  = smem + 64;       // 64
  int*   sL  = (int*)(smem + 128);  // 64
  float* hhL = smem + 192;      // 64*65 = 4160
  float* nfL = smem + 4352;     // 64*17 = 1088 -> ends 5440
  const int tid = threadIdx.x;
  const int e0 = blockIdx.x * 64;
  if (tid < 64) {
    uL[tid] = u_[e0 + tid];
    cL[tid] = cut_[e0 + tid];
    sL[tid] = esrc[e0 + tid];
  }
  __syncthreads();
  for (int i = tid; i < 64 * 64; i += 512) {
    const int e = i >> 6, k = i & 63;
    hhL[e * 65 + k] = fmaxf(fmaf(uL[e], W1[k], bvec[k]), 0.f) * cL[e];
  }
  for (int i = tid; i < 64 * 16; i += 512) {
    const int e = i >> 4, f = i & 15;
    nfL[e * 17 + f] = feat16[(size_t)sL[e] * 16 + f];
  }
  __syncthreads();

  const int lane = tid & 63, wv = tid >> 6;
  const int wq = wv & 3, kh = wv >> 2;
  const int lr = lane & 15, lg = lane >> 4;
  const int n0 = wq * 2;

  if (IS2 && kh == 0) {
    f32x4 sacc[4][2];
#pragma unroll
    for (int mt = 0; mt < 4; ++mt)
#pragma unroll
      for (int n = 0; n < 2; ++n) {
        f32x4 zz = {0.f, 0.f, 0.f, 0.f};
        sacc[mt][n] = zz;
      }
#pragma unroll
    for (int ks2 = 0; ks2 < 2; ++ks2) {
      half8 ash[4], asl[4];
#pragma unroll
      for (int mt = 0; mt < 4; ++mt) {
        float p[8];
        const float* hp = &hhL[(mt * 16 + lr) * 65 + ks2 * 32 + lg * 8];
#pragma unroll
        for (int j = 0; j < 8; ++j) p[j] = hp[j];
        split8h(p, ash[mt], asl[mt]);
      }
#pragma unroll
      for (int n = 0; n < 2; ++n) {
        const half8 bh = *(const half8*)&SWh[((n0 + n) * 16 + lr) * 64 + ks2 * 32 + lg * 8];
        const half8 bl = *(const half8*)&SWl[((n0 + n) * 16 + lr) * 64 + ks2 * 32 + lg * 8];
#pragma unroll
        for (int mt = 0; mt < 4; ++mt) {
          sacc[mt][n] = __builtin_amdgcn_mfma_f32_16x16x32_f16(ash[mt], bh, sacc[mt][n], 0, 0, 0);
          sacc[mt][n] = __builtin_amdgcn_mfma_f32_16x16x32_f16(asl[mt], bh, sacc[mt][n], 0, 0, 0);
          sacc[mt][n] = __builtin_amdgcn_mfma_f32_16x16x32_f16(ash[mt], bl, sacc[mt][n], 0, 0, 0);
        }
      }
    }
#pragma unroll
    for (int mt = 0; mt < 4; ++mt)
#pragma unroll
      for (int n = 0; n < 2; ++n)
#pragma unroll
        for (int i = 0; i < 4; ++i)
          self_[(size_t)(e0 + mt * 16 + lg * 4 + i) * 128 + (n0 + n) * 16 + lr] =
              sacc[mt][n][i] * 0.5f;
  }

  float nf8[4][8];
#pragma unroll
  for (int mt = 0; mt < 4; ++mt)
#pragma unroll
    for (int j = 0; j < 8; ++j)
      nf8[mt][j] = nfL[(mt * 16 + lr) * 17 + (lg & 1) * 8 + j];

  f32x4 acc[4][2];
#pragma unroll
  for (int mt = 0; mt < 4; ++mt)
#pragma unroll
    for (int n = 0; n < 2; ++n) {
      f32x4 zz = {0.f, 0.f, 0.f, 0.f};
      acc[mt][n] = zz;
    }

  const ushort* bh_base[2] = {
    &W2Th[(size_t)((n0 + 0) * 16 + lr) * 1024 + lg * 8],
    &W2Th[(size_t)((n0 + 1) * 16 + lr) * 1024 + lg * 8]};
  const ushort* bl_base[2] = {
    &W2Tl[(size_t)((n0 + 0) * 16 + lr) * 1024 + lg * 8],
    &W2Tl[(size_t)((n0 + 1) * 16 + lr) * 1024 + lg * 8]};
  const float* hs_base[4] = {&hhL[(0 * 16 + lr) * 65 + (lg >> 1)],
                             &hhL[(1 * 16 + lr) * 65 + (lg >> 1)],
                             &hhL[(2 * 16 + lr) * 65 + (lg >> 1)],
                             &hhL[(3 * 16 + lr) * 65 + (lg >> 1)]};

  const int ks0 = kh * 16, ks1 = ks0 + 16;
  half8 bhA[2], blA[2], bhB[2], blB[2];
  float hsA[4], hsB[4];
#pragma unroll
  for (int n = 0; n < 2; ++n) {
    bhA[n] = *(const half8*)(bh_base[n] + ks0 * 32);
    blA[n] = *(const half8*)(bl_base[n] + ks0 * 32);
  }
#pragma unroll
  for (int mt = 0; mt < 4; ++mt) hsA[mt] = hs_base[mt][2 * ks0];

  for (int ks = ks0; ks < ks1; ks += 2) {
#pragma unroll
    for (int n = 0; n < 2; ++n) {
      bhB[n] = *(const half8*)(bh_base[n] + (ks + 1) * 32);
      blB[n] = *(const half8*)(bl_base[n] + (ks + 1) * 32);
    }
#pragma unroll
    for (int mt = 0; mt < 4; ++mt) hsB[mt] = hs_base[mt][2 * (ks + 1)];
    MSG_STEP(hsA, bhA, blA);
    if (ks + 2 < ks1) {
#pragma unroll
      for (int n = 0; n < 2; ++n) {
        bhA[n] = *(const half8*)(bh_base[n] + (ks + 2) * 32);
        blA[n] = *(const half8*)(bl_base[n] + (ks + 2) * 32);
      }
#pragma unroll
      for (int mt = 0; mt < 4; ++mt) hsA[mt] = hs_base[mt][2 * (ks + 2)];
    }
    MSG_STEP(hsB, bhB, blB);
  }

  // combine K-halves via LDS (padded stride 33 -> conflict-free)
  __syncthreads();  // all waves done reading hhL/nfL; smem reusable
  if (kh == 1) {
#pragma unroll
    for (int mt = 0; mt < 4; ++mt)
#pragma unroll
      for (int n = 0; n < 2; ++n)
#pragma unroll
        for (int i = 0; i < 4; ++i)
          smem[wq * 2112 + lane * 33 + mt * 8 + n * 4 + i] = acc[mt][n][i];
  }
  __syncthreads();
  if (kh == 0) {
#pragma unroll
    for (int mt = 0; mt < 4; ++mt)
#pragma unroll
      for (int n = 0; n < 2; ++n)
#pragma unroll
        for (int i = 0; i < 4; ++i) {
          const float v = acc[mt][n][i] +
                          smem[wq * 2112 + lane * 33 + mt * 8 + n * 4 + i];
          t_[(size_t)(e0 + mt * 16 + lg * 4 + i) * 128 + (n0 + n) * 16 + lr] =
              v * 0.125f;  // 1/sqrt(F)/deg
        }
  }
}

// ---------------- gather: wave-per-node, no block barriers ----------------
__global__ __launch_bounds__(256) void k_gather1(
    const float* __restrict__ t_, const float* __restrict__ Y_,
    const int* __restrict__ offs, const int* __restrict__ elist,
    float* __restrict__ h1, float* __restrict__ h1s) {
  __shared__ float lds[4 * 176];
  const int tid = threadIdx.x, lane = tid & 63, wv = tid >> 6;
  const int n = blockIdx.x * 4 + wv;
  float* tW = &lds[wv * 176];
  float* YW = tW + 128;
  float* sW = tW + 144;
  const int beg = offs[n], end = offs[n + 1];
  int o0q[4], o1q[4], ccq[4];
#pragma unroll
  for (int q = 0; q < 4; ++q) {
    const int tv = lane + 64 * q;
    const int cc = tv & 15;
    ccq[q] = cc;
    o0q[q] = ((tv >> 4) << 2) + lidx_of(cc);
    o1q[q] = o0q[q] + 64;
  }
  float a0[4] = {0.f, 0.f, 0.f, 0.f}, a1[4] = {0.f, 0.f, 0.f, 0.f};
  for (int ei = beg; ei < end; ++ei) {
    const int e = elist[ei];
    const float2 v = *(const float2*)&t_[(size_t)e * 128 + lane * 2];
    tW[lane * 2] = v.x;
    tW[lane * 2 + 1] = v.y;
    if (lane < 16) YW[lane] = Y_[(size_t)e * 16 + lane];
    __builtin_amdgcn_wave_barrier();
#pragma unroll
    for (int q = 0; q < 4; ++q) {
      const float yv = YW[ccq[q]];
      a0[q] = fmaf(tW[o0q[q]], yv, a0[q]);
      a1[q] = fmaf(tW[o1q[q]], yv, a1[q]);
    }
    __builtin_amdgcn_wave_barrier();
  }
#pragma unroll
  for (int q = 0; q < 4; ++q)
    if (ccq[q] == 0) {
      const int tv = lane + 64 * q;
      sW[tv >> 4] = a0[q];
      sW[(tv >> 4) + 16] = a1[q];
    }
  __builtin_amdgcn_wave_barrier();
#pragma unroll
  for (int q = 0; q < 4; ++q) {
    const int tv = lane + 64 * q;
    const float s0 = sW[tv >> 4], s1 = sW[(tv >> 4) + 16];
    const float r0 = (ccq[q] == 0) ? fmaxf(a0[q], 0.f)
                                   : a0[q] * (1.f / (1.f + expf(-s0)));
    const float r1 = (ccq[q] == 0) ? fmaxf(a1[q], 0.f)
                                   : a1[q] * (1.f / (1.f + expf(-s1)));
    h1[(size_t)n * 512 + tv] = r0;
    h1[(size_t)n * 512 + tv + 256] = r1;
    if ((tv & 31) == 0) {
      h1s[n * 16 + (tv >> 5)] = r0;
      h1s[n * 16 + (tv >> 5) + 8] = r1;
    }
  }
}

__global__ __launch_bounds__(256) void k_gather2(
    const float* __restrict__ t_, const float* __restrict__ self_,
    const float* __restrict__ Y_, const float* __restrict__ h1,
    const int* __restrict__ offs, const int* __restrict__ elist,
    const int* __restrict__ esrc, float* __restrict__ h2) {
  __shared__ float lds[4 * 304];
  const int tid = threadIdx.x, lane = tid & 63, wv = tid >> 6;
  const int n = blockIdx.x * 4 + wv;
  float* tW = &lds[wv * 304];
  float* wL = tW + 128;
  float* YW = tW + 256;
  float* sW = tW + 272;
  const int beg = offs[n], end = offs[n + 1];
  int o0q[4], o1q[4], ccq[4];
#pragma unroll
  for (int q = 0; q < 4; ++q) {
    const int tv = lane + 64 * q;
    const int cc = tv & 15;
    ccq[q] = cc;
    o0q[q] = ((tv >> 4) << 2) + lidx_of(cc);
    o1q[q] = o0q[q] + 64;
  }
  float a0[4] = {0.f, 0.f, 0.f, 0.f}, a1[4] = {0.f, 0.f, 0.f, 0.f};
  for (int ei = beg; ei < end; ++ei) {
    const int e = elist[ei];
    const float2 v = *(const float2*)&t_[(size_t)e * 128 + lane * 2];
    const float2 w2 = *(const float2*)&self_[(size_t)e * 128 + lane * 2];
    tW[lane * 2] = v.x;
    tW[lane * 2 + 1] = v.y;
    wL[lane * 2] = w2.x;
    wL[lane * 2 + 1] = w2.y;
    if (lane < 16) YW[lane] = Y_[(size_t)e * 16 + lane];
    __builtin_amdgcn_wave_barrier();
    const int src = esrc[e];
    const float* hr = &h1[(size_t)src * 512];
#pragma unroll
    for (int q = 0; q < 4; ++q) {
      const int tv = lane + 64 * q;
      const float yv = YW[ccq[q]];
      a0[q] += tW[o0q[q]] * yv + hr[tv] * wL[o0q[q]];
      a1[q] += tW[o1q[q]] * yv + hr[tv + 256] * wL[o1q[q]];
    }
    __builtin_amdgcn_wave_barrier();
  }
#pragma unroll
  for (int q = 0; q < 4; ++q)
    if (ccq[q] == 0) {
      const int tv = lane + 64 * q;
      sW[tv >> 4] = a0[q];
      sW[(tv >> 4) + 16] = a1[q];
    }
  __builtin_amdgcn_wave_barrier();
#pragma unroll
  for (int q = 0; q < 4; ++q) {
    const int tv = lane + 64 * q;
    const float s0 = sW[tv >> 4], s1 = sW[(tv >> 4) + 16];
    const float r0 = (ccq[q] == 0) ? fmaxf(a0[q], 0.f)
                                   : a0[q] * (1.f / (1.f + expf(-s0)));
    const float r1 = (ccq[q] == 0) ? fmaxf(a1[q], 0.f)
                                   : a1[q] * (1.f / (1.f + expf(-s1)));
    h2[(size_t)n * 512 + tv] = r0;
    h2[(size_t)n * 512 + tv + 256] = r1;
  }
}

// ---------------- mean pool over each graph's 256 nodes ----------------
__global__ __launch_bounds__(256) void k_pool(const float* __restrict__ h2,
                                              float* __restrict__ enc) {
  const int b = blockIdx.x, tid = threadIdx.x;
  float a0 = 0.f, a1 = 0.f;
  for (int i = 0; i < 256; ++i) {
    const float* row = &h2[(size_t)(b * 256 + i) * 512];
    a0 += row[tid];
    a1 += row[tid + 256];
  }
  enc[b * 512 + tid] = a0 * (1.f / 256.f);
  enc[b * 512 + tid + 256] = a1 * (1.f / 256.f);
}

// ---------------- z = per-l linear mix of enc (B,32,16) -> (B,16,84) ----------------
__global__ __launch_bounds__(256) void k_zproj(const float* __restrict__ enc,
                                               const float* __restrict__ Wlin,
                                               float* __restrict__ z) {
  __shared__ float eL[512];
  const int b = blockIdx.x, tid = threadIdx.x;
  eL[tid] = enc[b * 512 + tid];
  eL[tid + 256] = enc[b * 512 + tid + 256];
  __syncthreads();
  for (int idx = tid; idx < 16 * 84; idx += 256) {
    const int g = idx / 84, d3 = idx % 84;
    int o0, m0, mo;
    if (d3 < 1)       { o0 = 0;  m0 = 1; mo = 0; }
    else if (d3 < 10) { o0 = 1;  m0 = 3; mo = 1; }
    else if (d3 < 35) { o0 = 10; m0 = 5; mo = 4; }
    else              { o0 = 35; m0 = 7; mo = 9; }
    const int rem = d3 - o0;
    const int jj = rem / m0;
    const int cc2 = rem - jj * m0;
    float a = 0.f;
    for (int mu = 0; mu < 32; ++mu)
      a = fmaf(eL[mu * 16 + mo + cc2], Wlin[(mu * 16 + g) * 16 + mo + jj], a);
    z[(size_t)(b * 16 + g) * 84 + d3] = a * 0.17677669529663687f;  // 1/sqrt(32)
  }
}

// ---------------- SO3 conv as split-bf16 MFMA GEMMs ----------------
template <int FI>
__global__ __launch_bounds__(256) void k_prep_xg(const float* __restrict__ x,
                                                 ushort* __restrict__ Xh,
                                                 ushort* __restrict__ Xl) {
  constexpr int KP0 = (FI + 31) & ~31, KP1 = (3 * FI + 31) & ~31;
  constexpr int KP2 = (5 * FI + 31) & ~31, KP3 = (7 * FI + 31) & ~31;
  constexpr int XO1 = 32 * KP0, XO2 = XO1 + 96 * KP1, XO3 = XO2 + 160 * KP2;
  constexpr int TOT = XO3 + 224 * KP3;
  const int idx = blockIdx.x * 256 + threadIdx.x;
  if (idx >= TOT) return;
  int m, o0, base, KP;
  if (idx < XO1)      { m = 1; o0 = 0;  base = 0;   KP = KP0; }
  else if (idx < XO2) { m = 3; o0 = 1;  base = XO1; KP = KP1; }
  else if (idx < XO3) { m = 5; o0 = 10; base = XO2; KP = KP2; }
  else                { m = 7; o0 = 35; base = XO3; KP = KP3; }
  const int rel = idx - base;
  const int r = rel / KP, k = rel % KP;
  ushort h = 0, lo = 0;
  if (k < FI * m) {
    const int f = k / m, i = k % m, b = r / m, c = r % m;
    const float v = x[((size_t)b * FI + f) * 84 + o0 + i * m + c];
    h = f2bf(v);
    lo = (ushort)(__float_as_uint(v - bf2f(h)) >> 16);
  }
  Xh[idx] = h;
  Xl[idx] = lo;
}

template <int FI, int FO>
__global__ __launch_bounds__(256) void k_prep_psig(const float* __restrict__ psi,
                                                   ushort* __restrict__ Ph,
                                                   ushort* __restrict__ Pl) {
  constexpr int KP0 = (FI + 31) & ~31, KP1 = (3 * FI + 31) & ~31;
  constexpr int KP2 = (5 * FI + 31) & ~31, KP3 = (7 * FI + 31) & ~31;
  constexpr int PO1 = FO * KP0, PO2 = PO1 + 3 * FO * KP1, PO3 = PO2 + 5 * FO * KP2;
  constexpr int TOT = PO3 + 7 * FO * KP3;
  const int idx = blockIdx.x * 256 + threadIdx.x;
  if (idx >= TOT) return;
  int m, o0, base, KP;
  if (idx < PO1)      { m = 1; o0 = 0;  base = 0;   KP = KP0; }
  else if (idx < PO2) { m = 3; o0 = 1;  base = PO1; KP = KP1; }
  else if (idx < PO3) { m = 5; o0 = 10; base = PO2; KP = KP2; }
  else                { m = 7; o0 = 35; base = PO3; KP = KP3; }
  const int rel = idx - base;
  const int n = rel / KP, k = rel % KP;
  ushort h = 0, lo = 0;
  if (k < FI * m) {
    const int f = k / m, i = k % m, g = n / KP0 * 0 + n / m, j = n % m;
    const float v = psi[((size_t)f * FO + (n / m)) * 84 + o0 + i * m + j];
    (void)g;
    h = f2bf(v);
    lo = (ushort)(__float_as_uint(v - bf2f(h)) >> 16);
  }
  Ph[idx] = h;
  Pl[idx] = lo;
}

template <int FI, int FO>
__global__ __launch_bounds__(256) void k_conv_gemm(
    const ushort* __restrict__ Xh, const ushort* __restrict__ Xl,
    const ushort* __restrict__ Ph, const ushort* __restrict__ Pl,
    float* __restrict__ out) {
  constexpr int KP0 = (FI + 31) & ~31, KP1 = (3 * FI + 31) & ~31;
  constexpr int KP2 = (5 * FI + 31) & ~31, KP3 = (7 * FI + 31) & ~31;
  constexpr int XO1 = 32 * KP0, XO2 = XO1 + 96 * KP1, XO3 = XO2 + 160 * KP2;
  constexpr int PO1 = FO * KP0, PO2 = PO1 + 3 * FO * KP1, PO3 = PO2 + 5 * FO * KP2;
  constexpr int NT0 = 1 * (FO / 32), NT1 = 3 * (3 * FO / 32);
  constexpr int NT2 = 5 * (5 * FO / 32), NT3 = 7 * (7 * FO / 32);
  constexpr int TB1 = NT0, TB2 = TB1 + NT1, TB3 = TB2 + NT2, TOT = TB3 + NT3;

  const int wt = blockIdx.x * 4 + (threadIdx.x >> 6);
  if (wt >= TOT) return;
  int m, o0, Mt, KP, Xo, Po, loc;
  if (wt < TB1)      { m = 1; o0 = 0;  Mt = 1; KP = KP0; Xo = 0;   Po = 0;   loc = wt; }
  else if (wt < TB2) { m = 3; o0 = 1;  Mt = 3; KP = KP1; Xo = XO1; Po = PO1; loc = wt - TB1; }
  else if (wt < TB3) { m = 5; o0 = 10; Mt = 5; KP = KP2; Xo = XO2; Po = PO2; loc = wt - TB2; }
  else               { m = 7; o0 = 35; Mt = 7; KP = KP3; Xo = XO3; Po = PO3; loc = wt - TB3; }
  const int mt0 = (loc % Mt) * 32;
  const int nt0 = (loc / Mt) * 32;
  const int lane = threadIdx.x & 63, lr = lane & 15, lg = lane >> 4;

  f32x4 acc[2][2];
#pragma unroll
  for (int mt = 0; mt < 2; ++mt)
#pragma unroll
    for (int nt = 0; nt < 2; ++nt) {
      f32x4 zz = {0.f, 0.f, 0.f, 0.f};
      acc[mt][nt] = zz;
    }

  const int nks = KP >> 5;
  for (int ks = 0; ks < nks; ++ks) {
    short8 ah[2], al[2], bh[2], bl[2];
#pragma unroll
    for (int t = 0; t < 2; ++t) {
      const size_t xa = (size_t)Xo + (size_t)(mt0 + t * 16 + lr) * KP + ks * 32 + lg * 8;
      ah[t] = *(const short8*)&Xh[xa];
      al[t] = *(const short8*)&Xl[xa];
      const size_t pa = (size_t)Po + (size_t)(nt0 + t * 16 + lr) * KP + ks * 32 + lg * 8;
      bh[t] = *(const short8*)&Ph[pa];
      bl[t] = *(const short8*)&Pl[pa];
    }
#pragma unroll
    for (int nt = 0; nt < 2; ++nt)
#pragma unroll
      for (int mt = 0; mt < 2; ++mt) {
        acc[mt][nt] = __builtin_amdgcn_mfma_f32_16x16x32_bf16(ah[mt], bh[nt], acc[mt][nt], 0, 0, 0);
        acc[mt][nt] = __builtin_amdgcn_mfma_f32_16x16x32_bf16(al[mt], bh[nt], acc[mt][nt], 0, 0, 0);
        acc[mt][nt] = __builtin_amdgcn_mfma_f32_16x16x32_bf16(ah[mt], bl[nt], acc[mt][nt], 0, 0, 0);
      }
  }

  const float scale = 1.f / sqrtf((float)(FI * m));
#pragma unroll
  for (int mt = 0; mt < 2; ++mt)
#pragma unroll
    for (int nt = 0; nt < 2; ++nt)
#pragma unroll
      for (int i = 0; i < 4; ++i) {
        const int R = mt0 + mt * 16 + lg * 4 + i;
        const int C2 = nt0 + nt * 16 + lr;
        const int b = R / m, c = R - b * m;
        const int g = C2 / m, j = C2 - g * m;
        out[((size_t)b * FO + g) * 84 + o0 + j * m + c] = acc[mt][nt][i] * scale;
      }
}

// ---------------- weight prep for MFMA act ----------------
__global__ __launch_bounds__(256) void k_prep_gt(const float* __restrict__ Gt,
                                                 ushort* __restrict__ GtT) {
  const int idx = blockIdx.x * 256 + threadIdx.x;
  if (idx >= 4096 * 96) return;
  const int g = idx / 96, k = idx % 96;
  GtT[idx] = (k < 84) ? f2bf(Gt[(size_t)k * 4096 + g]) : (ushort)0;
}
__global__ __launch_bounds__(256) void k_prep_gf(const float* __restrict__ Gf,
                                                 ushort* __restrict__ GfT) {
  const int idx = blockIdx.x * 256 + threadIdx.x;
  if (idx >= 96 * 4096) return;
  const int d = idx / 4096, g = idx % 4096;
  GfT[idx] = (d < 84) ? f2bf(Gf[(size_t)g * 84 + d]) : (ushort)0;
}
__global__ __launch_bounds__(256) void k_cvtx(const float* __restrict__ x,
                                              ushort* __restrict__ Xb, int total) {
  const int idx = blockIdx.x * 256 + threadIdx.x;
  if (idx >= total) return;
  const int r = idx / 96, k = idx % 96;
  Xb[idx] = (k < 84) ? f2bf(x[(size_t)r * 84 + k]) : (ushort)0;
}

// ---------------- SO3 act via bf16 MFMA (fused, g-split partials) ----------------
template <int GS>
__global__ __launch_bounds__(256) void k_act_mfma(
    const ushort* __restrict__ Xb, const ushort* __restrict__ GtT,
    const ushort* __restrict__ GfT, float* __restrict__ part, int NR) {
  constexpr int CPB = 64 / GS;
  __shared__ __align__(16) ushort ldsGt[64 * 104];
  __shared__ __align__(16) ushort ldsH[128 * 72];
  __shared__ __align__(16) ushort ldsGf[96 * 72];
  const int tid = threadIdx.x;
  const int gs = blockIdx.x;
  const int row0 = blockIdx.y * 128;
  const int lane = tid & 63, wv = tid >> 6;
  const int lr = lane & 15, lg = lane >> 4;
  const int m0 = wv * 32;

  short8 a1[2][3];
#pragma unroll
  for (int mt = 0; mt < 2; ++mt)
#pragma unroll
    for (int ks = 0; ks < 3; ++ks)
      a1[mt][ks] = *(const short8*)&Xb[(size_t)(row0 + m0 + mt * 16 + lr) * 96 +
                                       ks * 32 + lg * 8];

  f32x4 acc2[6][2];
#pragma unroll
  for (int m2 = 0; m2 < 6; ++m2)
#pragma unroll
    for (int n2 = 0; n2 < 2; ++n2) {
      f32x4 zz = {0.f, 0.f, 0.f, 0.f};
      acc2[m2][n2] = zz;
    }

  for (int ch = gs * CPB; ch < (gs + 1) * CPB; ++ch) {
    const int g0 = ch * 64;
    __syncthreads();
    for (int i = tid; i < 768; i += 256) {
      const int row = i / 12, c = i % 12;
      *(uint4*)&ldsGt[row * 104 + c * 8] =
          *(const uint4*)&GtT[(size_t)(g0 + row) * 96 + c * 8];
    }
    for (int i = tid; i < 768; i += 256) {
      const int row = i / 8, c = i % 8;
      *(uint4*)&ldsGf[row * 72 + c * 8] =
          *(const uint4*)&GfT[(size_t)row * 4096 + g0 + c * 8];
    }
    __syncthreads();
#pragma unroll
    for (int n = 0; n < 4; ++n) {
      short8 b[3];
#pragma unroll
      for (int ks = 0; ks < 3; ++ks)
        b[ks] = *(const short8*)&ldsGt[(n * 16 + lr) * 104 + ks * 32 + lg * 8];
#pragma unroll
      for (int mt = 0; mt < 2; ++mt) {
        f32x4 c1 = {0.f, 0.f, 0.f, 0.f};
#pragma unroll
        for (int ks = 0; ks < 3; ++ks)
          c1 = __builtin_amdgcn_mfma_f32_16x16x32_bf16(a1[mt][ks], b[ks], c1, 0, 0, 0);
        ushort* hp = &ldsH[(m0 + mt * 16 + lg * 4) * 72 + n * 16 + lr];
#pragma unroll
        for (int i = 0; i < 4; ++i) hp[i * 72] = f2bf(fmaxf(c1[i], 0.f));
      }
    }
#pragma unroll
    for (int k2 = 0; k2 < 2; ++k2) {
      short8 bh[2];
#pragma unroll
      for (int n2 = 0; n2 < 2; ++n2)
        bh[n2] = *(const short8*)&ldsH[(m0 + n2 * 16 + lr) * 72 + k2 * 32 + lg * 8];
#pragma unroll
      for (int m2 = 0; m2 < 6; ++m2) {
        const short8 a2 = *(const short8*)&ldsGf[(m2 * 16 + lr) * 72 + k2 * 32 + lg * 8];
        acc2[m2][0] = __builtin_amdgcn_mfma_f32_16x16x32_bf16(a2, bh[0], acc2[m2][0], 0, 0, 0);
        acc2[m2][1] = __builtin_amdgcn_mfma_f32_16x16x32_bf16(a2, bh[1], acc2[m2][1], 0, 0, 0);
      }
    }
  }
#pragma unroll
  for (int m2 = 0; m2 < 6; ++m2)
#pragma unroll
    for (int n2 = 0; n2 < 2; ++n2)
#pragma unroll
      for (int i = 0; i < 4; ++i) {
        const int d = m2 * 16 + lg * 4 + i;
        if (d < 84) {
          const int r = row0 + m0 + n2 * 16 + lr;
          part[((size_t)gs * NR + r) * 84 + d] = acc2[m2][n2][i];
        }
      }
}

template <int GS>
__global__ __launch_bounds__(256) void k_act_reduce(const float* __restrict__ part,
                                                    float* __restrict__ out, int total) {
  const int i = blockIdx.x * 256 + threadIdx.x;
  if (i < total) {
    float s = part[i];
#pragma unroll
    for (int g = 1; g < GS; ++g) s += part[(size_t)g * total + i];
    out[i] = s * (1.f / (9.16515138991168f * 64.f));
  }
}

// ---------------- final: Ws2 contraction + orientation SH dot ----------------
__global__ __launch_bounds__(256) void k_final(const float* __restrict__ x,
                                               const float* __restrict__ Ws2,
                                               const float* __restrict__ orient,
                                               float* __restrict__ outp) {
  __shared__ float red[256][16];
  const int b = blockIdx.x, tid = threadIdx.x;
  const float* xr = &x[(size_t)(b * 256 + tid) * 84];
  const float* wr = &Ws2[tid * 16];
  float acc[16];
#pragma unroll
  for (int c = 0; c < 16; ++c) acc[c] = 0.f;
  acc[0] = fmaf(xr[0], wr[0], acc[0]);
#pragma unroll
  for (int i = 0; i < 3; ++i) {
    const float w = wr[1 + i];
#pragma unroll
    for (int c = 0; c < 3; ++c) acc[1 + c] = fmaf(xr[1 + i * 3 + c], w, acc[1 + c]);
  }
#pragma unroll
  for (int i = 0; i < 5; ++i) {
    const float w = wr[4 + i];
#pragma unroll
    for (int c = 0; c < 5; ++c) acc[4 + c] = fmaf(xr[10 + i * 5 + c], w, acc[4 + c]);
  }
#pragma unroll
  for (int i = 0; i < 7; ++i) {
    const float w = wr[9 + i];
#pragma unroll
    for (int c = 0; c < 7; ++c) acc[9 + c] = fmaf(xr[35 + i * 7 + c], w, acc[9 + c]);
  }
#pragma unroll
  for (int c = 0; c < 16; ++c) red[tid][c] = acc[c];
  __syncthreads();
  for (int off = 128; off > 0; off >>= 1) {
    if (tid < off)
#pragma unroll
      for (int c = 0; c < 16; ++c) red[tid][c] += red[tid + off][c];
    __syncthreads();
  }
  if (tid == 0) {
    const float aa = orient[b * 2 + 0], rr = orient[b * 2 + 1];
    float Y[16];
    real_sh_f(-sinf(aa) * cosf(rr), -sinf(aa) * sinf(rr), -cosf(aa), Y);
    const float sc1 = 1.f / 16.f;
    const float sc3 = 1.f / (16.f * 1.7320508075688772f);
    const float sc5 = 1.f / (16.f * 2.23606797749979f);
    const float sc7 = 1.f / (16.f * 2.6457513110645907f);
    float o = red[0][0] * sc1 * Y[0];
#pragma unroll
    for (int c = 1; c < 4; ++c) o += red[0][c] * sc3 * Y[c];
#pragma unroll
    for (int c = 4; c < 9; ++c) o += red[0][c] * sc5 * Y[c];
#pragma unroll
    for (int c = 9; c < 16; ++c) o += red[0][c] * sc7 * Y[c];
    outp[b] = o;
  }
}

extern "C" void kernel_launch(void* const* d_in, const int* in_sizes, int n_in,
                              void* d_out, int out_size, void* d_ws, size_t ws_size,
                              hipStream_t stream) {
  const float* node_feat = (const float*)d_in[0];
  const float* pos       = (const float*)d_in[1];
  const float* orient    = (const float*)d_in[2];
  const float* rad1_W1   = (const float*)d_in[3];
  const float* rad1_b    = (const float*)d_in[4];
  const float* rad1_W2   = (const float*)d_in[5];
  const float* rad2_W1   = (const float*)d_in[6];
  const float* rad2_b    = (const float*)d_in[7];
  const float* rad2_W2   = (const float*)d_in[8];
  const float* Wlin      = (const float*)d_in[9];
  const float* psi1      = (const float*)d_in[10];
  const float* psi2      = (const float*)d_in[11];
  const float* psi3      = (const float*)d_in[12];
  const float* G_to      = (const float*)d_in[13];
  const float* G_from    = (const float*)d_in[14];
  const float* Ws2       = (const float*)d_in[15];
  const int*   esrc      = (const int*)d_in[16];
  const int*   edst      = (const int*)d_in[17];

  float* w = (float*)d_ws;
  size_t off = 0;
  float* u_    = w + off; off += NE;
  float* cut_  = w + off; off += NE;
  float* Y_    = w + off; off += (size_t)NE * 16;   // later: Xp hi/lo (bf16)
  float* t_    = w + off; off += (size_t)NE * 128;  // t1/t2; later act partials
  float* self_ = w + off; off += (size_t)NE * 128;
  float* h1    = w + off; off += (size_t)NN * 512;  // later: GtT/GfT/Xb (bf16)
  float* h1s   = w + off; off += (size_t)NN * 16;
  float* h2    = w + off; off += (size_t)NN * 512;  // later: Psi-p hi/lo (bf16)
  float* enc   = w + off; off += (size_t)NB * 512;
  float* z     = w + off; off += (size_t)NB * 16 * 84;
  float* xb1   = w + off; off += (size_t)NB * 256 * 84;
  float* xb2   = w + off; off += (size_t)NB * 256 * 84;
  int* cnt    = (int*)(w + off); off += NN;
  int* offs   = (int*)(w + off); off += NN + 1;
  int* cursor = (int*)(w + off); off += NN;
  int* elist  = (int*)(w + off); off += NE;
  ushort* W2Th = (ushort*)(w + off); off += 65536;
  ushort* W2Tl = (ushort*)(w + off); off += 65536;
  ushort* SWh  = (ushort*)(w + off); off += 4096;
  ushort* SWl  = (ushort*)(w + off); off += 4096;

  // reuse of dead buffers during conv/act chain:
  float* part = t_;
  ushort* GtT = (ushort*)h1;
  ushort* GfT = GtT + 4096 * 96;
  ushort* Xb  = GfT + 96 * 4096;
  ushort* Xph = (ushort*)Y_;
  ushort* Xpl = Xph + 344064;
  ushort* Pph = (ushort*)h2;
  ushort* Ppl = Pph + 2752512;

  hipMemsetAsync(cnt, 0, NN * sizeof(int), stream);
  k_edge_prep<<<NE / 256, 256, 0, stream>>>(pos, esrc, edst, u_, cut_, Y_, cnt);
  k_scan<<<1, 256, 0, stream>>>(cnt, offs, cursor);
  k_fill<<<NE / 256, 256, 0, stream>>>(edst, cursor, elist);

  k_prep_w2t<false><<<512, 256, 0, stream>>>(rad1_W2, W2Th, W2Tl);
  k_msg_mfma<false><<<NE / 64, 512, 0, stream>>>(u_, cut_, rad1_W1, rad1_b, W2Th, W2Tl,
                                                 nullptr, nullptr, node_feat, esrc,
                                                 t_, nullptr);
  k_gather1<<<NN / 4, 256, 0, stream>>>(t_, Y_, offs, elist, h1, h1s);

  k_prep_w2t<true><<<512, 256, 0, stream>>>(rad2_W2, W2Th, W2Tl);
  k_prep_selfw<<<32, 256, 0, stream>>>(rad2_W2, SWh, SWl);
  k_msg_mfma<true><<<NE / 64, 512, 0, stream>>>(u_, cut_, rad2_W1, rad2_b, W2Th, W2Tl,
                                                SWh, SWl, h1s, esrc, t_, self_);
  k_gather2<<<NN / 4, 256, 0, stream>>>(t_, self_, Y_, h1, offs, elist, esrc, h2);
  k_pool<<<NB, 256, 0, stream>>>(h2, enc);
  k_zproj<<<NB, 256, 0, stream>>>(enc, Wlin, z);

  k_prep_gt<<<(4096 * 96 + 255) / 256, 256, 0, stream>>>(G_to, GtT);
  k_prep_gf<<<(96 * 4096 + 255) / 256, 256, 0, stream>>>(G_from, GfT);

  // ---- stage 1
  k_prep_psig<16, 64><<<(102400 + 255) / 256, 256, 0, stream>>>(psi1, Pph, Ppl);
  k_prep_xg<16><<<(51200 + 255) / 256, 256, 0, stream>>>(z, Xph, Xpl);
  k_conv_gemm<16, 64><<<42, 256, 0, stream>>>(Xph, Xpl, Pph, Ppl, xb1);
  k_cvtx<<<(2048 * 96 + 255) / 256, 256, 0, stream>>>(xb1, Xb, 2048 * 96);
  k_act_mfma<32><<<dim3(32, 16), 256, 0, stream>>>(Xb, GtT, GfT, part, 2048);
  k_act_reduce<32><<<(2048 * 84 + 255) / 256, 256, 0, stream>>>(part, xb2, 2048 * 84);

  // ---- stage 2
  k_prep_psig<64, 128><<<(688128 + 255) / 256, 256, 0, stream>>>(psi2, Pph, Ppl);
  k_prep_xg<64><<<(172032 + 255) / 256, 256, 0, stream>>>(xb2, Xph, Xpl);
  k_conv_gemm<64, 128><<<84, 256, 0, stream>>>(Xph, Xpl, Pph, Ppl, xb1);
  k_cvtx<<<(4096 * 96 + 255) / 256, 256, 0, stream>>>(xb1, Xb, 4096 * 96);
  k_act_mfma<16><<<dim3(16, 32), 256, 0, stream>>>(Xb, GtT, GfT, part, 4096);
  k_act_reduce<16><<<(4096 * 84 + 255) / 256, 256, 0, stream>>>(part, xb2, 4096 * 84);

  // ---- stage 3
  k_prep_psig<128, 256><<<(2752512 + 255) / 256, 256, 0, stream>>>(psi3, Pph, Ppl);
  k_prep_xg<128><<<(344064 + 255) / 256, 256, 0, stream>>>(xb2, Xph, Xpl);
  k_conv_gemm<128, 256><<<168, 256, 0, stream>>>(Xph, Xpl, Pph, Ppl, xb1);
  k_cvtx<<<(8192 * 96 + 255) / 256, 256, 0, stream>>>(xb1, Xb, 8192 * 96);
  k_act_mfma<8><<<dim3(8, 64), 256, 0, stream>>>(Xb, GtT, GfT, part, 8192);
  k_act_reduce<8><<<(8192 * 84 + 255) / 256, 256, 0, stream>>>(part, xb2, 8192 * 84);

  k_final<<<NB, 256, 0, stream>>>(xb2, Ws2, orient, (float*)d_out);
}